// Round 1
// baseline (377.728 us; speedup 1.0000x reference)
//
#include <hip/hip_runtime.h>
#include <hip/hip_bf16.h>
#include <stdint.h>

typedef unsigned short u16;
typedef __attribute__((ext_vector_type(8))) short bf16x8;
typedef __attribute__((ext_vector_type(4))) float f32x4;
typedef __attribute__((ext_vector_type(4))) u16 u16x4;
typedef __attribute__((ext_vector_type(4))) float f4v;

#define DEV __device__ __forceinline__

DEV u16 f2bf(float x) {
    union { float f; uint32_t u; } v; v.f = x;
    uint32_t r = v.u + 0x7FFF + ((v.u >> 16) & 1);
    return (u16)(r >> 16);
}
DEV float bf2f(u16 b) {
    union { uint32_t u; float f; } v; v.u = ((uint32_t)b) << 16;
    return v.f;
}

DEV f32x4 mfma16(bf16x8 a, bf16x8 b, f32x4 c) {
    return __builtin_amdgcn_mfma_f32_16x16x32_bf16(a, b, c, 0, 0, 0);
}

DEV void gld_lds16(const u16* g, u16* lds) {
    __builtin_amdgcn_global_load_lds(
        (const __attribute__((address_space(1))) void*)g,
        (__attribute__((address_space(3))) void*)lds, 16, 0, 0);
}

// ---------------- Pass A: fp32 -> bf16 hi/lo split ----------------
struct SplitArgs {
    const float* src[3];
    u16* hi[3];
    u16* lo[3];
    int n4;
};

__global__ __launch_bounds__(256) void split_kernel(SplitArgs a) {
    const int z = blockIdx.y;
    const f4v* __restrict__ src = (const f4v*)a.src[z];
    u16x4* __restrict__ hi = (u16x4*)a.hi[z];
    u16x4* __restrict__ lo = (u16x4*)a.lo[z];
    int i = blockIdx.x * blockDim.x + threadIdx.x;
    const int stride = gridDim.x * blockDim.x;
    for (; i < a.n4; i += stride) {
        f4v x = src[i];
        u16x4 h, l;
#pragma unroll
        for (int c = 0; c < 4; ++c) {
            float xv = x[c];
            u16 hb = f2bf(xv);
            float r = xv - bf2f(hb);
            h[c] = hb;
            l[c] = f2bf(r);
        }
        hi[i] = h;
        lo[i] = l;
    }
}

// ---------------- Pass B: projections (split bf16 GEMM, 3 terms) ----------------
// C[m][e] = sum_d X[m][d] * W[e][d],  m = b*2048+s (M=4096), e = h*64+dk (N=1024), K=1024
// z=0: q (store qh[n][s][dk], transposed-D epilogue), z=1: k (same), z=2: v (store vt[n][dk][s])
struct ProjArgs {
    const u16* xhi[3];
    const u16* xlo[3];
    const u16* whi[3];
    const u16* wlo[3];
    u16* outq;
    u16* outk;
    u16* outvt;
};

__global__ __launch_bounds__(256) void proj_kernel(ProjArgs args) {
    __shared__ u16 As[128 * 32];   // X tile, rows m, 32 K-elems (64B) per row
    __shared__ u16 Bs[128 * 32];   // W tile, rows e

    const int z = blockIdx.z;
    const int tid = threadIdx.x;
    const int w = tid >> 6, l = tid & 63;
    const int m0 = blockIdx.x * 128, e0 = blockIdx.y * 128;
    const int wri = w >> 1, wci = w & 1;     // wave 2x2 -> 64x64 subtile
    const int fr = l & 15, fg = l >> 4;

    const u16* Xh = args.xhi[z];
    const u16* Xl = args.xlo[z];
    const u16* Wh = args.whi[z];
    const u16* Wl = args.wlo[z];

    f32x4 acc[4][4];
#pragma unroll
    for (int mi = 0; mi < 4; ++mi)
#pragma unroll
        for (int ni = 0; ni < 4; ++ni)
            acc[mi][ni] = (f32x4){0.f, 0.f, 0.f, 0.f};

    // staging geometry: wave w covers rows [w*32, w*32+32); lane l -> row offset l>>2, 16B chunk (l&3)
    const int srow = w * 32 + (l >> 2);
    const int scol = (l & 3) * 8;  // elements

    const bool swap = (z < 2);

    for (int t = 0; t < 3; ++t) {
        const u16* Ap = (t == 2) ? Xl : Xh;
        const u16* Bp = (t == 1) ? Wl : Wh;
        for (int kb = 0; kb < 32; ++kb) {
            __syncthreads();
#pragma unroll
            for (int j = 0; j < 2; ++j) {
                gld_lds16(Ap + (size_t)(m0 + srow + j * 16) * 1024 + kb * 32 + scol,
                          &As[w * 1024 + j * 512]);
                gld_lds16(Bp + (size_t)(e0 + srow + j * 16) * 1024 + kb * 32 + scol,
                          &Bs[w * 1024 + j * 512]);
            }
            __syncthreads();

            const u16* SA = swap ? Bs : As;
            const u16* SB = swap ? As : Bs;
            bf16x8 af[4], bf_[4];
#pragma unroll
            for (int mi = 0; mi < 4; ++mi)
                af[mi] = *(const bf16x8*)&SA[(wri * 64 + mi * 16 + fr) * 32 + fg * 8];
#pragma unroll
            for (int ni = 0; ni < 4; ++ni)
                bf_[ni] = *(const bf16x8*)&SB[(wci * 64 + ni * 16 + fr) * 32 + fg * 8];
#pragma unroll
            for (int mi = 0; mi < 4; ++mi)
#pragma unroll
                for (int ni = 0; ni < 4; ++ni)
                    acc[mi][ni] = mfma16(af[mi], bf_[ni], acc[mi][ni]);
        }
    }

    u16* outp = (z == 0) ? args.outq : (z == 1) ? args.outk : args.outvt;

    if (swap) {
        // D[e][m]: e = e0 + wri*64 + mi*16 + fg*4 + r ; m = m0 + wci*64 + ni*16 + fr
#pragma unroll
        for (int mi = 0; mi < 4; ++mi) {
#pragma unroll
            for (int ni = 0; ni < 4; ++ni) {
                int e = e0 + wri * 64 + mi * 16 + fg * 4;
                int m = m0 + wci * 64 + ni * 16 + fr;
                int b = m >> 11, s = m & 2047;
                int n = b * 16 + (e >> 6);
                u16x4 pk;
#pragma unroll
                for (int r = 0; r < 4; ++r) pk[r] = f2bf(acc[mi][ni][r]);
                *(u16x4*)&outp[((size_t)(n * 2048 + s)) * 64 + (e & 63)] = pk;
            }
        }
    } else {
        // D[m][e]: m = m0 + wri*64 + mi*16 + fg*4 + r ; e = e0 + wci*64 + ni*16 + fr
#pragma unroll
        for (int mi = 0; mi < 4; ++mi) {
#pragma unroll
            for (int ni = 0; ni < 4; ++ni) {
                int m = m0 + wri * 64 + mi * 16 + fg * 4;
                int e = e0 + wci * 64 + ni * 16 + fr;
                int b = m >> 11;
                int n = b * 16 + (e >> 6), dk = e & 63;
                u16x4 pk;
#pragma unroll
                for (int r = 0; r < 4; ++r) pk[r] = f2bf(acc[mi][ni][r]);
                *(u16x4*)&outp[((size_t)(n * 64 + dk)) * 2048 + (m & 2047)] = pk;
            }
        }
    }
}

// ---------------- Pass C: flash attention ----------------
// qh[n][s][d] (bf16), kh[n][s][d] (bf16), vt[n][d][s] (bf16) -> out fp32 with chunk-scramble.
// Block: 4 waves; wave owns 16 q-rows. Loop 16 chunks of 128 keys.
__global__ __launch_bounds__(256) void attn_kernel(const u16* __restrict__ qh,
                                                   const u16* __restrict__ kh,
                                                   const u16* __restrict__ vt,
                                                   float* __restrict__ out) {
    __shared__ u16 Plds[4][16 * 136];  // per-wave P buffer, pitch 136 (272B: 16B-aligned, 2-way banks)

    const int tid = threadIdx.x;
    const int w = tid >> 6, l = tid & 63;
    const int fr = l & 15, fg = l >> 4;
    const int n = blockIdx.y;                 // head-batch 0..31 (= b*16 + h)
    const int qbase = blockIdx.x * 64 + w * 16;
    const float cs = 0.125f * 1.44269504088896f;  // (1/sqrt(dk)) * log2(e)

    // Q fragments (row = fr, k = d)
    const u16* qrow = qh + ((size_t)n * 2048 + qbase + fr) * 64;
    bf16x8 aq0 = *(const bf16x8*)(qrow + fg * 8);
    bf16x8 aq1 = *(const bf16x8*)(qrow + 32 + fg * 8);

    f32x4 acc[4];
#pragma unroll
    for (int dc = 0; dc < 4; ++dc) acc[dc] = (f32x4){0.f, 0.f, 0.f, 0.f};
    float mrun[4], lrun[4];
#pragma unroll
    for (int r = 0; r < 4; ++r) { mrun[r] = -INFINITY; lrun[r] = 0.f; }

    u16* P = Plds[w];

    for (int kb = 0; kb < 16; ++kb) {
        // ---- scores for 128 keys: 8 fragments of 16 keys ----
        f32x4 sf[8];
#pragma unroll
        for (int c = 0; c < 8; ++c) {
            const u16* krow = kh + ((size_t)n * 2048 + kb * 128 + c * 16 + fr) * 64;
            f32x4 s = (f32x4){0.f, 0.f, 0.f, 0.f};
            s = mfma16(aq0, *(const bf16x8*)(krow + fg * 8), s);
            s = mfma16(aq1, *(const bf16x8*)(krow + 32 + fg * 8), s);
            sf[c] = s * cs;
        }
        // ---- chunk max per row (reduce over 8 frags, then 16 lanes) ----
        f32x4 cm = sf[0];
#pragma unroll
        for (int c = 1; c < 8; ++c)
#pragma unroll
            for (int r = 0; r < 4; ++r) cm[r] = fmaxf(cm[r], sf[c][r]);
#pragma unroll
        for (int m = 1; m < 16; m <<= 1)
#pragma unroll
            for (int r = 0; r < 4; ++r) cm[r] = fmaxf(cm[r], __shfl_xor(cm[r], m, 64));

        float sc[4];
#pragma unroll
        for (int r = 0; r < 4; ++r) {
            float mnew = fmaxf(mrun[r], cm[r]);
            sc[r] = exp2f(mrun[r] - mnew);
            mrun[r] = mnew;
        }
#pragma unroll
        for (int dc = 0; dc < 4; ++dc)
#pragma unroll
            for (int r = 0; r < 4; ++r) acc[dc][r] *= sc[r];

        // ---- p = exp2(s - m), write P to LDS, accumulate row sums ----
        f32x4 ps = (f32x4){0.f, 0.f, 0.f, 0.f};
#pragma unroll
        for (int c = 0; c < 8; ++c) {
#pragma unroll
            for (int r = 0; r < 4; ++r) {
                float p = exp2f(sf[c][r] - mrun[r]);
                ps[r] += p;
                P[(fg * 4 + r) * 136 + c * 16 + fr] = f2bf(p);
            }
        }
#pragma unroll
        for (int m = 1; m < 16; m <<= 1)
#pragma unroll
            for (int r = 0; r < 4; ++r) ps[r] += __shfl_xor(ps[r], m, 64);
#pragma unroll
        for (int r = 0; r < 4; ++r) lrun[r] = lrun[r] * sc[r] + ps[r];

        // ---- PV: out[q][d] += P[q][key] * V[key][d] ----
#pragma unroll
        for (int th = 0; th < 4; ++th) {
            bf16x8 ap = *(const bf16x8*)&P[fr * 136 + th * 32 + fg * 8];
#pragma unroll
            for (int dc = 0; dc < 4; ++dc) {
                const u16* vrow = vt + ((size_t)n * 64 + dc * 16 + fr) * 2048 +
                                  kb * 128 + th * 32 + fg * 8;
                acc[dc] = mfma16(ap, *(const bf16x8*)vrow, acc[dc]);
            }
        }
    }

    // ---- finalize: divide by l, store with chunk-scramble ----
    float inv[4];
#pragma unroll
    for (int r = 0; r < 4; ++r) inv[r] = 1.f / lrun[r];
    const int bq = n & 1;
    const int col0 = (n >> 1) * 64;
    float* orow = out + ((size_t)bq * 2048 + qbase + fg * 4) * 1024 + col0;
#pragma unroll
    for (int dc = 0; dc < 4; ++dc)
#pragma unroll
        for (int r = 0; r < 4; ++r)
            orow[(size_t)r * 1024 + dc * 16 + fr] = acc[dc][r] * inv[r];
}

// ---------------- launch ----------------
extern "C" void kernel_launch(void* const* d_in, const int* in_sizes, int n_in,
                              void* d_out, int out_size, void* d_ws, size_t ws_size,
                              hipStream_t stream) {
    (void)n_in; (void)out_size; (void)ws_size;
    const float* q  = (const float*)d_in[0];
    const float* k  = (const float*)d_in[1];
    const float* v  = (const float*)d_in[2];
    const float* Wq = (const float*)d_in[3];
    const float* Wk = (const float*)d_in[4];
    const float* Wv = (const float*)d_in[5];

    uint8_t* ws = (uint8_t*)d_ws;
    const size_t MB = 1024ull * 1024ull;
    // ws layout (needs 84 MB):
    u16* xq_hi = (u16*)(ws + 0 * MB);
    u16* xq_lo = (u16*)(ws + 8 * MB);
    u16* xk_hi = (u16*)(ws + 16 * MB);
    u16* xk_lo = (u16*)(ws + 24 * MB);
    u16* xv_hi = (u16*)(ws + 32 * MB);
    u16* xv_lo = (u16*)(ws + 40 * MB);
    u16* wq_hi = (u16*)(ws + 48 * MB);
    u16* wq_lo = (u16*)(ws + 50 * MB);
    u16* wk_hi = (u16*)(ws + 52 * MB);
    u16* wk_lo = (u16*)(ws + 54 * MB);
    u16* wv_hi = (u16*)(ws + 56 * MB);
    u16* wv_lo = (u16*)(ws + 58 * MB);
    u16* qh    = (u16*)(ws + 60 * MB);
    u16* kh    = (u16*)(ws + 68 * MB);
    u16* vt    = (u16*)(ws + 76 * MB);

    SplitArgs sx;
    sx.src[0] = q;  sx.src[1] = k;  sx.src[2] = v;
    sx.hi[0] = xq_hi; sx.hi[1] = xk_hi; sx.hi[2] = xv_hi;
    sx.lo[0] = xq_lo; sx.lo[1] = xk_lo; sx.lo[2] = xv_lo;
    sx.n4 = in_sizes[0] / 4;
    split_kernel<<<dim3(2048, 3), 256, 0, stream>>>(sx);

    SplitArgs sw;
    sw.src[0] = Wq; sw.src[1] = Wk; sw.src[2] = Wv;
    sw.hi[0] = wq_hi; sw.hi[1] = wk_hi; sw.hi[2] = wv_hi;
    sw.lo[0] = wq_lo; sw.lo[1] = wk_lo; sw.lo[2] = wv_lo;
    sw.n4 = in_sizes[3] / 4;
    split_kernel<<<dim3(1024, 3), 256, 0, stream>>>(sw);

    ProjArgs pa;
    pa.xhi[0] = xq_hi; pa.xhi[1] = xk_hi; pa.xhi[2] = xv_hi;
    pa.xlo[0] = xq_lo; pa.xlo[1] = xk_lo; pa.xlo[2] = xv_lo;
    pa.whi[0] = wq_hi; pa.whi[1] = wk_hi; pa.whi[2] = wv_hi;
    pa.wlo[0] = wq_lo; pa.wlo[1] = wk_lo; pa.wlo[2] = wv_lo;
    pa.outq = qh; pa.outk = kh; pa.outvt = vt;
    proj_kernel<<<dim3(32, 8, 3), 256, 0, stream>>>(pa);

    attn_kernel<<<dim3(32, 32), 256, 0, stream>>>(qh, kh, vt, (float*)d_out);
}

// Round 2
// 374.656 us; speedup vs baseline: 1.0082x; 1.0082x over previous
//
#include <hip/hip_runtime.h>
#include <hip/hip_bf16.h>
#include <stdint.h>

typedef unsigned short u16;
typedef __attribute__((ext_vector_type(8))) short bf16x8;
typedef __attribute__((ext_vector_type(4))) float f32x4;
typedef __attribute__((ext_vector_type(4))) u16 u16x4;
typedef __attribute__((ext_vector_type(4))) float f4v;

#define DEV __device__ __forceinline__

DEV u16 f2bf(float x) {
    union { float f; uint32_t u; } v; v.f = x;
    uint32_t r = v.u + 0x7FFF + ((v.u >> 16) & 1);
    return (u16)(r >> 16);
}
DEV float bf2f(u16 b) {
    union { uint32_t u; float f; } v; v.u = ((uint32_t)b) << 16;
    return v.f;
}

DEV f32x4 mfma16(bf16x8 a, bf16x8 b, f32x4 c) {
    return __builtin_amdgcn_mfma_f32_16x16x32_bf16(a, b, c, 0, 0, 0);
}

DEV void gld_lds16(const u16* g, u16* lds) {
    __builtin_amdgcn_global_load_lds(
        (const __attribute__((address_space(1))) void*)g,
        (__attribute__((address_space(3))) void*)lds, 16, 0, 0);
}

// ---------------- Pass A: fp32 -> bf16 hi/lo split ----------------
struct SplitArgs {
    const float* src[3];
    u16* hi[3];
    u16* lo[3];
    int n4;
};

__global__ __launch_bounds__(256) void split_kernel(SplitArgs a) {
    const int z = blockIdx.y;
    const f4v* __restrict__ src = (const f4v*)a.src[z];
    u16x4* __restrict__ hi = (u16x4*)a.hi[z];
    u16x4* __restrict__ lo = (u16x4*)a.lo[z];
    int i = blockIdx.x * blockDim.x + threadIdx.x;
    const int stride = gridDim.x * blockDim.x;
    for (; i < a.n4; i += stride) {
        f4v x = src[i];
        u16x4 h, l;
#pragma unroll
        for (int c = 0; c < 4; ++c) {
            float xv = x[c];
            u16 hb = f2bf(xv);
            float r = xv - bf2f(hb);
            h[c] = hb;
            l[c] = f2bf(r);
        }
        hi[i] = h;
        lo[i] = l;
    }
}

// ---------------- Pass B: projections (split bf16 GEMM, 3 terms) ----------------
struct ProjArgs {
    const u16* xhi[3];
    const u16* xlo[3];
    const u16* whi[3];
    const u16* wlo[3];
    u16* outq;
    u16* outk;
    u16* outvt;
};

__global__ __launch_bounds__(256) void proj_kernel(ProjArgs args) {
    __shared__ u16 As[128 * 32];
    __shared__ u16 Bs[128 * 32];

    const int z = blockIdx.z;
    const int tid = threadIdx.x;
    const int w = tid >> 6, l = tid & 63;
    const int m0 = blockIdx.x * 128, e0 = blockIdx.y * 128;
    const int wri = w >> 1, wci = w & 1;
    const int fr = l & 15, fg = l >> 4;

    const u16* Xh = args.xhi[z];
    const u16* Xl = args.xlo[z];
    const u16* Wh = args.whi[z];
    const u16* Wl = args.wlo[z];

    f32x4 acc[4][4];
#pragma unroll
    for (int mi = 0; mi < 4; ++mi)
#pragma unroll
        for (int ni = 0; ni < 4; ++ni)
            acc[mi][ni] = (f32x4){0.f, 0.f, 0.f, 0.f};

    const int srow = w * 32 + (l >> 2);
    const int scol = (l & 3) * 8;

    const bool swap = (z < 2);

    for (int t = 0; t < 3; ++t) {
        const u16* Ap = (t == 2) ? Xl : Xh;
        const u16* Bp = (t == 1) ? Wl : Wh;
        for (int kb = 0; kb < 32; ++kb) {
            __syncthreads();
#pragma unroll
            for (int j = 0; j < 2; ++j) {
                gld_lds16(Ap + (size_t)(m0 + srow + j * 16) * 1024 + kb * 32 + scol,
                          &As[w * 1024 + j * 512]);
                gld_lds16(Bp + (size_t)(e0 + srow + j * 16) * 1024 + kb * 32 + scol,
                          &Bs[w * 1024 + j * 512]);
            }
            __syncthreads();

            const u16* SA = swap ? Bs : As;
            const u16* SB = swap ? As : Bs;
            bf16x8 af[4], bf_[4];
#pragma unroll
            for (int mi = 0; mi < 4; ++mi)
                af[mi] = *(const bf16x8*)&SA[(wri * 64 + mi * 16 + fr) * 32 + fg * 8];
#pragma unroll
            for (int ni = 0; ni < 4; ++ni)
                bf_[ni] = *(const bf16x8*)&SB[(wci * 64 + ni * 16 + fr) * 32 + fg * 8];
#pragma unroll
            for (int mi = 0; mi < 4; ++mi)
#pragma unroll
                for (int ni = 0; ni < 4; ++ni)
                    acc[mi][ni] = mfma16(af[mi], bf_[ni], acc[mi][ni]);
        }
    }

    u16* outp = (z == 0) ? args.outq : (z == 1) ? args.outk : args.outvt;

    if (swap) {
#pragma unroll
        for (int mi = 0; mi < 4; ++mi) {
#pragma unroll
            for (int ni = 0; ni < 4; ++ni) {
                int e = e0 + wri * 64 + mi * 16 + fg * 4;
                int m = m0 + wci * 64 + ni * 16 + fr;
                int b = m >> 11, s = m & 2047;
                int n = b * 16 + (e >> 6);
                u16x4 pk;
#pragma unroll
                for (int r = 0; r < 4; ++r) pk[r] = f2bf(acc[mi][ni][r]);
                *(u16x4*)&outp[((size_t)(n * 2048 + s)) * 64 + (e & 63)] = pk;
            }
        }
    } else {
#pragma unroll
        for (int mi = 0; mi < 4; ++mi) {
#pragma unroll
            for (int ni = 0; ni < 4; ++ni) {
                int m = m0 + wri * 64 + mi * 16 + fg * 4;
                int e = e0 + wci * 64 + ni * 16 + fr;
                int b = m >> 11;
                int n = b * 16 + (e >> 6), dk = e & 63;
                u16x4 pk;
#pragma unroll
                for (int r = 0; r < 4; ++r) pk[r] = f2bf(acc[mi][ni][r]);
                *(u16x4*)&outp[((size_t)(n * 64 + dk)) * 2048 + (m & 2047)] = pk;
            }
        }
    }
}

// ---------------- Pass C: flash attention, swapped-QK^T, all in-register ----------------
// qh[n][s][d], kh[n][s][d], vt[n][d][s] (bf16) -> out fp32 with chunk-scramble.
// Wave owns 16 q-rows; each lane owns ONE q-row (q = qbase + (lane&15)).
// K rows are loaded in permuted order sigma(c,i) = 32*(c>>1) + (i>>2)*8 + (c&1)*4 + (i&3)
// so that the swapped-QK output register layout coincides exactly with the PV
// A-operand layout (slot fg*8+j <-> key 32*p + fg*8 + j). No LDS, no barriers.
__global__ __launch_bounds__(256, 4) void attn_kernel(const u16* __restrict__ qh,
                                                      const u16* __restrict__ kh,
                                                      const u16* __restrict__ vt,
                                                      float* __restrict__ out) {
    const int tid = threadIdx.x;
    const int w = tid >> 6, l = tid & 63;
    const int fr = l & 15, fg = l >> 4;
    const int n = blockIdx.y;                 // head-batch 0..31 (= b*16 + h)
    const int qbase = blockIdx.x * 64 + w * 16;
    const float cs = 0.125f * 1.44269504088896f;  // (1/sqrt(dk)) * log2(e)

    // Q fragments (B-operand: row = q = fr, dims fg*8..)
    const u16* qrow = qh + ((size_t)n * 2048 + qbase + fr) * 64;
    bf16x8 aq0 = *(const bf16x8*)(qrow + fg * 8);
    bf16x8 aq1 = *(const bf16x8*)(qrow + 32 + fg * 8);

    const u16* khn = kh + (size_t)n * 2048 * 64;
    const u16* vtn = vt + (size_t)n * 64 * 2048;

    f32x4 acc[4];
#pragma unroll
    for (int dc = 0; dc < 4; ++dc) acc[dc] = (f32x4){0.f, 0.f, 0.f, 0.f};
    float mrun = -INFINITY;
    float lrun = 0.f;

    const int rowperm = ((fr >> 2) << 3) + (fr & 3);  // lane-constant part of sigma

    for (int kb = 0; kb < 16; ++kb) {
        // ---- swapped scores: S^T = K*Q^T; lane holds 32 scores of row q=fr ----
        f32x4 sf[8];
#pragma unroll
        for (int c = 0; c < 8; ++c) {
            const int krow = kb * 128 + ((c >> 1) << 5) + ((c & 1) << 2) + rowperm;
            const u16* kr = khn + (size_t)krow * 64;
            f32x4 s = (f32x4){0.f, 0.f, 0.f, 0.f};
            s = mfma16(*(const bf16x8*)(kr + fg * 8), aq0, s);
            s = mfma16(*(const bf16x8*)(kr + 32 + fg * 8), aq1, s);
            sf[c] = s;
        }

        // ---- row max: lane-local over 32, then across the 4 fg-groups ----
        f32x4 cmv = sf[0];
#pragma unroll
        for (int c = 1; c < 8; ++c)
#pragma unroll
            for (int r = 0; r < 4; ++r) cmv[r] = fmaxf(cmv[r], sf[c][r]);
        float cm = fmaxf(fmaxf(cmv[0], cmv[1]), fmaxf(cmv[2], cmv[3]));
        cm = fmaxf(cm, __shfl_xor(cm, 16, 64));
        cm = fmaxf(cm, __shfl_xor(cm, 32, 64));

        // ---- online rescale (exact skip when no lane's max grew) ----
        if (__any(cm > mrun)) {
            float mnew = fmaxf(mrun, cm);
            float sc = exp2f(cs * (mrun - mnew));
            mrun = mnew;
            lrun *= sc;
            float scq[4];
#pragma unroll
            for (int r = 0; r < 4; ++r) scq[r] = __shfl(sc, fg * 4 + r, 64);
#pragma unroll
            for (int dc = 0; dc < 4; ++dc)
#pragma unroll
                for (int r = 0; r < 4; ++r) acc[dc][r] *= scq[r];
        }

        // ---- p = exp2(cs*s - cs*m); lane-local partial sums ----
        const float negm = -cs * mrun;
        f32x4 psv = (f32x4){0.f, 0.f, 0.f, 0.f};
#pragma unroll
        for (int c = 0; c < 8; ++c) {
            f32x4 p;
#pragma unroll
            for (int r = 0; r < 4; ++r) p[r] = exp2f(fmaf(cs, sf[c][r], negm));
            psv += p;
            sf[c] = p;
        }
        lrun += (psv[0] + psv[1]) + (psv[2] + psv[3]);

        // ---- PV: pack P windows (layout already matches A-operand) ----
#pragma unroll
        for (int pw = 0; pw < 4; ++pw) {
            bf16x8 ap;
#pragma unroll
            for (int j = 0; j < 8; ++j)
                ap[j] = (short)f2bf(sf[2 * pw + (j >> 2)][j & 3]);
#pragma unroll
            for (int dc = 0; dc < 4; ++dc) {
                const u16* vr = vtn + (size_t)(dc * 16 + fr) * 2048 +
                                kb * 128 + pw * 32 + fg * 8;
                acc[dc] = mfma16(ap, *(const bf16x8*)vr, acc[dc]);
            }
        }
    }

    // ---- finalize: row sums across fg-groups, divide, store scrambled ----
    lrun += __shfl_xor(lrun, 16, 64);
    lrun += __shfl_xor(lrun, 32, 64);
    float inv = 1.f / lrun;
    float invq[4];
#pragma unroll
    for (int r = 0; r < 4; ++r) invq[r] = __shfl(inv, fg * 4 + r, 64);

    const int bq = n & 1;
    const int col0 = (n >> 1) * 64;
    float* orow = out + ((size_t)bq * 2048 + qbase + fg * 4) * 1024 + col0;
#pragma unroll
    for (int dc = 0; dc < 4; ++dc)
#pragma unroll
        for (int r = 0; r < 4; ++r)
            orow[(size_t)r * 1024 + dc * 16 + fr] = acc[dc][r] * invq[r];
}

// ---------------- launch ----------------
extern "C" void kernel_launch(void* const* d_in, const int* in_sizes, int n_in,
                              void* d_out, int out_size, void* d_ws, size_t ws_size,
                              hipStream_t stream) {
    (void)n_in; (void)out_size; (void)ws_size;
    const float* q  = (const float*)d_in[0];
    const float* k  = (const float*)d_in[1];
    const float* v  = (const float*)d_in[2];
    const float* Wq = (const float*)d_in[3];
    const float* Wk = (const float*)d_in[4];
    const float* Wv = (const float*)d_in[5];

    uint8_t* ws = (uint8_t*)d_ws;
    const size_t MB = 1024ull * 1024ull;
    u16* xq_hi = (u16*)(ws + 0 * MB);
    u16* xq_lo = (u16*)(ws + 8 * MB);
    u16* xk_hi = (u16*)(ws + 16 * MB);
    u16* xk_lo = (u16*)(ws + 24 * MB);
    u16* xv_hi = (u16*)(ws + 32 * MB);
    u16* xv_lo = (u16*)(ws + 40 * MB);
    u16* wq_hi = (u16*)(ws + 48 * MB);
    u16* wq_lo = (u16*)(ws + 50 * MB);
    u16* wk_hi = (u16*)(ws + 52 * MB);
    u16* wk_lo = (u16*)(ws + 54 * MB);
    u16* wv_hi = (u16*)(ws + 56 * MB);
    u16* wv_lo = (u16*)(ws + 58 * MB);
    u16* qh    = (u16*)(ws + 60 * MB);
    u16* kh    = (u16*)(ws + 68 * MB);
    u16* vt    = (u16*)(ws + 76 * MB);

    SplitArgs sx;
    sx.src[0] = q;  sx.src[1] = k;  sx.src[2] = v;
    sx.hi[0] = xq_hi; sx.hi[1] = xk_hi; sx.hi[2] = xv_hi;
    sx.lo[0] = xq_lo; sx.lo[1] = xk_lo; sx.lo[2] = xv_lo;
    sx.n4 = in_sizes[0] / 4;
    split_kernel<<<dim3(2048, 3), 256, 0, stream>>>(sx);

    SplitArgs sw;
    sw.src[0] = Wq; sw.src[1] = Wk; sw.src[2] = Wv;
    sw.hi[0] = wq_hi; sw.hi[1] = wk_hi; sw.hi[2] = wv_hi;
    sw.lo[0] = wq_lo; sw.lo[1] = wk_lo; sw.lo[2] = wv_lo;
    sw.n4 = in_sizes[3] / 4;
    split_kernel<<<dim3(1024, 3), 256, 0, stream>>>(sw);

    ProjArgs pa;
    pa.xhi[0] = xq_hi; pa.xhi[1] = xk_hi; pa.xhi[2] = xv_hi;
    pa.xlo[0] = xq_lo; pa.xlo[1] = xk_lo; pa.xlo[2] = xv_lo;
    pa.whi[0] = wq_hi; pa.whi[1] = wk_hi; pa.whi[2] = wv_hi;
    pa.wlo[0] = wq_lo; pa.wlo[1] = wk_lo; pa.wlo[2] = wv_lo;
    pa.outq = qh; pa.outk = kh; pa.outvt = vt;
    proj_kernel<<<dim3(32, 8, 3), 256, 0, stream>>>(pa);

    attn_kernel<<<dim3(32, 32), 256, 0, stream>>>(qh, kh, vt, (float*)d_out);
}

// Round 3
// 213.251 us; speedup vs baseline: 1.7713x; 1.7569x over previous
//
#include <hip/hip_runtime.h>
#include <hip/hip_bf16.h>
#include <stdint.h>

typedef unsigned short u16;
typedef __attribute__((ext_vector_type(8))) short bf16x8;
typedef __attribute__((ext_vector_type(4))) float f32x4;
typedef __attribute__((ext_vector_type(4))) u16 u16x4;
typedef __attribute__((ext_vector_type(4))) float f4v;

#define DEV __device__ __forceinline__

DEV u16 f2bf(float x) {
    union { float f; uint32_t u; } v; v.f = x;
    uint32_t r = v.u + 0x7FFF + ((v.u >> 16) & 1);
    return (u16)(r >> 16);
}
DEV float bf2f(u16 b) {
    union { uint32_t u; float f; } v; v.u = ((uint32_t)b) << 16;
    return v.f;
}

DEV f32x4 mfma16(bf16x8 a, bf16x8 b, f32x4 c) {
    return __builtin_amdgcn_mfma_f32_16x16x32_bf16(a, b, c, 0, 0, 0);
}

DEV void gld_lds16(const u16* g, u16* lds) {
    __builtin_amdgcn_global_load_lds(
        (const __attribute__((address_space(1))) void*)g,
        (__attribute__((address_space(3))) void*)lds, 16, 0, 0);
}

// ---------------- Pass A: fp32 -> bf16 hi/lo split ----------------
struct SplitArgs {
    const float* src[3];
    u16* hi[3];
    u16* lo[3];
    int n4;
};

__global__ __launch_bounds__(256) void split_kernel(SplitArgs a) {
    const int z = blockIdx.y;
    const f4v* __restrict__ src = (const f4v*)a.src[z];
    u16x4* __restrict__ hi = (u16x4*)a.hi[z];
    u16x4* __restrict__ lo = (u16x4*)a.lo[z];
    int i = blockIdx.x * blockDim.x + threadIdx.x;
    const int stride = gridDim.x * blockDim.x;
    for (; i < a.n4; i += stride) {
        f4v x = src[i];
        u16x4 h, l;
#pragma unroll
        for (int c = 0; c < 4; ++c) {
            float xv = x[c];
            u16 hb = f2bf(xv);
            float r = xv - bf2f(hb);
            h[c] = hb;
            l[c] = f2bf(r);
        }
        hi[i] = h;
        lo[i] = l;
    }
}

// ---------------- Pass B: projections (split bf16 GEMM, 3 terms) ----------------
struct ProjArgs {
    const u16* xhi[3];
    const u16* xlo[3];
    const u16* whi[3];
    const u16* wlo[3];
    u16* outq;
    u16* outk;
    u16* outvt;
};

__global__ __launch_bounds__(256) void proj_kernel(ProjArgs args) {
    __shared__ u16 As[128 * 32];
    __shared__ u16 Bs[128 * 32];

    const int z = blockIdx.z;
    const int tid = threadIdx.x;
    const int w = tid >> 6, l = tid & 63;
    const int m0 = blockIdx.x * 128, e0 = blockIdx.y * 128;
    const int wri = w >> 1, wci = w & 1;
    const int fr = l & 15, fg = l >> 4;

    const u16* Xh = args.xhi[z];
    const u16* Xl = args.xlo[z];
    const u16* Wh = args.whi[z];
    const u16* Wl = args.wlo[z];

    f32x4 acc[4][4];
#pragma unroll
    for (int mi = 0; mi < 4; ++mi)
#pragma unroll
        for (int ni = 0; ni < 4; ++ni)
            acc[mi][ni] = (f32x4){0.f, 0.f, 0.f, 0.f};

    const int srow = w * 32 + (l >> 2);
    const int scol = (l & 3) * 8;

    const bool swap = (z < 2);

    for (int t = 0; t < 3; ++t) {
        const u16* Ap = (t == 2) ? Xl : Xh;
        const u16* Bp = (t == 1) ? Wl : Wh;
        for (int kb = 0; kb < 32; ++kb) {
            __syncthreads();
#pragma unroll
            for (int j = 0; j < 2; ++j) {
                gld_lds16(Ap + (size_t)(m0 + srow + j * 16) * 1024 + kb * 32 + scol,
                          &As[w * 1024 + j * 512]);
                gld_lds16(Bp + (size_t)(e0 + srow + j * 16) * 1024 + kb * 32 + scol,
                          &Bs[w * 1024 + j * 512]);
            }
            __syncthreads();

            const u16* SA = swap ? Bs : As;
            const u16* SB = swap ? As : Bs;
            bf16x8 af[4], bf_[4];
#pragma unroll
            for (int mi = 0; mi < 4; ++mi)
                af[mi] = *(const bf16x8*)&SA[(wri * 64 + mi * 16 + fr) * 32 + fg * 8];
#pragma unroll
            for (int ni = 0; ni < 4; ++ni)
                bf_[ni] = *(const bf16x8*)&SB[(wci * 64 + ni * 16 + fr) * 32 + fg * 8];
#pragma unroll
            for (int mi = 0; mi < 4; ++mi)
#pragma unroll
                for (int ni = 0; ni < 4; ++ni)
                    acc[mi][ni] = mfma16(af[mi], bf_[ni], acc[mi][ni]);
        }
    }

    u16* outp = (z == 0) ? args.outq : (z == 1) ? args.outk : args.outvt;

    if (swap) {
#pragma unroll
        for (int mi = 0; mi < 4; ++mi) {
#pragma unroll
            for (int ni = 0; ni < 4; ++ni) {
                int e = e0 + wri * 64 + mi * 16 + fg * 4;
                int m = m0 + wci * 64 + ni * 16 + fr;
                int b = m >> 11, s = m & 2047;
                int n = b * 16 + (e >> 6);
                u16x4 pk;
#pragma unroll
                for (int r = 0; r < 4; ++r) pk[r] = f2bf(acc[mi][ni][r]);
                *(u16x4*)&outp[((size_t)(n * 2048 + s)) * 64 + (e & 63)] = pk;
            }
        }
    } else {
#pragma unroll
        for (int mi = 0; mi < 4; ++mi) {
#pragma unroll
            for (int ni = 0; ni < 4; ++ni) {
                int m = m0 + wri * 64 + mi * 16 + fg * 4;
                int e = e0 + wci * 64 + ni * 16 + fr;
                int b = m >> 11;
                int n = b * 16 + (e >> 6), dk = e & 63;
                u16x4 pk;
#pragma unroll
                for (int r = 0; r < 4; ++r) pk[r] = f2bf(acc[mi][ni][r]);
                *(u16x4*)&outp[((size_t)(n * 64 + dk)) * 2048 + (m & 2047)] = pk;
            }
        }
    }
}

// ---------------- Pass C: flash attention, LDS-staged, double-buffered ----------------
// 8 waves/block, 128 q-rows/block. K/V chunk (128 keys) staged in LDS with
// additive slot-rotation swizzle (conflict-free b128 reads+writes).
// Swapped QK^T + sigma-permuted key order => softmax fully lane-local.
__global__ __launch_bounds__(512, 4) void attn_kernel(const u16* __restrict__ qh,
                                                      const u16* __restrict__ kh,
                                                      const u16* __restrict__ vt,
                                                      float* __restrict__ out) {
    // [buf][ K: 128 rows x 64 elems | V: 64 rows x 128 elems ]
    __shared__ u16 lds[2][16384];

    const int tid = threadIdx.x;
    const int w = tid >> 6, l = tid & 63;
    const int fr = l & 15, fg = l >> 4;

    // head-clustered XCD mapping: XCD x owns heads 4x..4x+3 (K/V L2-resident)
    const int b = blockIdx.x;
    const int n = (b & 7) * 4 + ((b >> 3) >> 4);   // head-batch 0..31
    const int qt = (b >> 3) & 15;
    const int qbase = qt * 128 + w * 16;
    const float cs = 0.125f * 1.44269504088896f;   // (1/sqrt(dk)) * log2(e)

    const u16* khn = kh + (size_t)n * 2048 * 64;
    const u16* vtn = vt + (size_t)n * 64 * 2048;

    // Q fragments (B-operand: row = q = fr)
    const u16* qrow = qh + ((size_t)n * 2048 + qbase + fr) * 64;
    bf16x8 aq0 = *(const bf16x8*)(qrow + fg * 8);
    bf16x8 aq1 = *(const bf16x8*)(qrow + 32 + fg * 8);

    // ---- staging geometry (all 512 threads) ----
    const int krow_s = tid >> 2;               // 0..127
    const int kcol_s = (tid & 3) * 16;         // global elem offset in row
    const int kg_s = ((tid >> 2) & 3) + 4 * ((tid >> 5) & 1);
    const int kws0 = ((((tid & 3) * 2 + 0) + kg_s) & 7) * 8;   // swizzled elem slots
    const int kws1 = ((((tid & 3) * 2 + 1) + kg_s) & 7) * 8;
    const int vrow_s = tid >> 3;               // 0..63
    const int vcol_s = (tid & 7) * 16;
    const int vg_s = (tid >> 3) & 7;
    const int vws0 = ((((tid & 7) * 2 + 0) + vg_s) & 15) * 8;
    const int vws1 = ((((tid & 7) * 2 + 1) + vg_s) & 15) * 8;

    // ---- read-side swizzled slot offsets (lane-constant) ----
    const int rbase = ((fr >> 2) << 3) + (fr & 3);  // sigma row base
    const int kg_r = (fr & 3) + 4 * ((fr >> 2) & 1);
    const int ksl0 = (((fg + 0) + kg_r) & 7) * 8;
    const int ksl1 = (((fg + 4) + kg_r) & 7) * 8;
    const int vg_r = fr & 7;

    f32x4 acc[4];
#pragma unroll
    for (int dc = 0; dc < 4; ++dc) acc[dc] = (f32x4){0.f, 0.f, 0.f, 0.f};
    float mrun = -INFINITY;
    float lrun = 0.f;

    bf16x8 kr0, kr1, vr0, vr1;

#define STAGE_LOAD(kb_) do {                                                       \
        const u16* ksrc = khn + ((size_t)((kb_) * 128 + krow_s)) * 64 + kcol_s;    \
        kr0 = *(const bf16x8*)(ksrc);                                              \
        kr1 = *(const bf16x8*)(ksrc + 8);                                          \
        const u16* vsrc = vtn + (size_t)vrow_s * 2048 + (kb_) * 128 + vcol_s;      \
        vr0 = *(const bf16x8*)(vsrc);                                              \
        vr1 = *(const bf16x8*)(vsrc + 8);                                          \
    } while (0)

#define STAGE_WRITE(buf_) do {                                                     \
        u16* kp = &lds[buf_][0];                                                   \
        *(bf16x8*)&kp[krow_s * 64 + kws0] = kr0;                                   \
        *(bf16x8*)&kp[krow_s * 64 + kws1] = kr1;                                   \
        u16* vp = &lds[buf_][8192];                                                \
        *(bf16x8*)&vp[vrow_s * 128 + vws0] = vr0;                                  \
        *(bf16x8*)&vp[vrow_s * 128 + vws1] = vr1;                                  \
    } while (0)

    STAGE_LOAD(0);
    STAGE_WRITE(0);
    STAGE_LOAD(1);
    __syncthreads();

    for (int kb = 0; kb < 16; ++kb) {
        const int cur = kb & 1;
        const u16* Kb = &lds[cur][0];
        const u16* Vb = &lds[cur][8192];

        // ---- swapped scores: lane holds 32 scores of its q-row ----
        f32x4 sf[8];
#pragma unroll
        for (int c = 0; c < 8; ++c) {
            const int r = ((c >> 1) << 5) + ((c & 1) << 2) + rbase;
            f32x4 s = (f32x4){0.f, 0.f, 0.f, 0.f};
            s = mfma16(*(const bf16x8*)&Kb[r * 64 + ksl0], aq0, s);
            s = mfma16(*(const bf16x8*)&Kb[r * 64 + ksl1], aq1, s);
            sf[c] = s;
        }

        // ---- row max ----
        f32x4 cmv = sf[0];
#pragma unroll
        for (int c = 1; c < 8; ++c)
#pragma unroll
            for (int r = 0; r < 4; ++r) cmv[r] = fmaxf(cmv[r], sf[c][r]);
        float cm = fmaxf(fmaxf(cmv[0], cmv[1]), fmaxf(cmv[2], cmv[3]));
        cm = fmaxf(cm, __shfl_xor(cm, 16, 64));
        cm = fmaxf(cm, __shfl_xor(cm, 32, 64));

        // ---- online rescale (exact skip when no lane's max grew) ----
        if (__any(cm > mrun)) {
            float mnew = fmaxf(mrun, cm);
            float sc = exp2f(cs * (mrun - mnew));
            mrun = mnew;
            lrun *= sc;
            float scq[4];
#pragma unroll
            for (int r = 0; r < 4; ++r) scq[r] = __shfl(sc, fg * 4 + r, 64);
#pragma unroll
            for (int dc = 0; dc < 4; ++dc)
#pragma unroll
                for (int r = 0; r < 4; ++r) acc[dc][r] *= scq[r];
        }

        // ---- p = exp2(cs*s - cs*m) ----
        const float negm = -cs * mrun;
        f32x4 psv = (f32x4){0.f, 0.f, 0.f, 0.f};
#pragma unroll
        for (int c = 0; c < 8; ++c) {
            f32x4 p;
#pragma unroll
            for (int r = 0; r < 4; ++r) p[r] = exp2f(fmaf(cs, sf[c][r], negm));
            psv += p;
            sf[c] = p;
        }
        lrun += (psv[0] + psv[1]) + (psv[2] + psv[3]);

        // ---- PV ----
#pragma unroll
        for (int pw = 0; pw < 4; ++pw) {
            union { bf16x8 v; uint32_t u[4]; } ap;
#pragma unroll
            for (int q2 = 0; q2 < 4; ++q2) {
                float lo = sf[2 * pw + (q2 >> 1)][(q2 & 1) * 2 + 0];
                float hi = sf[2 * pw + (q2 >> 1)][(q2 & 1) * 2 + 1];
                asm("v_cvt_pk_bf16_f32 %0, %1, %2" : "=v"(ap.u[q2]) : "v"(lo), "v"(hi));
            }
#pragma unroll
            for (int dc = 0; dc < 4; ++dc) {
                const int vsl = (((pw * 4 + fg) + vg_r) & 15) * 8;
                acc[dc] = mfma16(ap.v, *(const bf16x8*)&Vb[(dc * 16 + fr) * 128 + vsl],
                                 acc[dc]);
            }
        }

        // ---- stage next chunk ----
        if (kb < 15) {
            __syncthreads();
            STAGE_WRITE(cur ^ 1);
            if (kb < 14) STAGE_LOAD(kb + 2);
            __syncthreads();
        }
    }

    // ---- finalize ----
    lrun += __shfl_xor(lrun, 16, 64);
    lrun += __shfl_xor(lrun, 32, 64);
    float inv = 1.f / lrun;
    float invq[4];
#pragma unroll
    for (int r = 0; r < 4; ++r) invq[r] = __shfl(inv, fg * 4 + r, 64);

    const int bq = n & 1;
    const int col0 = (n >> 1) * 64;
    float* orow = out + ((size_t)bq * 2048 + qbase + fg * 4) * 1024 + col0;
#pragma unroll
    for (int dc = 0; dc < 4; ++dc)
#pragma unroll
        for (int r = 0; r < 4; ++r)
            orow[(size_t)r * 1024 + dc * 16 + fr] = acc[dc][r] * invq[r];
#undef STAGE_LOAD
#undef STAGE_WRITE
}

// ---------------- launch ----------------
extern "C" void kernel_launch(void* const* d_in, const int* in_sizes, int n_in,
                              void* d_out, int out_size, void* d_ws, size_t ws_size,
                              hipStream_t stream) {
    (void)n_in; (void)out_size; (void)ws_size;
    const float* q  = (const float*)d_in[0];
    const float* k  = (const float*)d_in[1];
    const float* v  = (const float*)d_in[2];
    const float* Wq = (const float*)d_in[3];
    const float* Wk = (const float*)d_in[4];
    const float* Wv = (const float*)d_in[5];

    uint8_t* ws = (uint8_t*)d_ws;
    const size_t MB = 1024ull * 1024ull;
    u16* xq_hi = (u16*)(ws + 0 * MB);
    u16* xq_lo = (u16*)(ws + 8 * MB);
    u16* xk_hi = (u16*)(ws + 16 * MB);
    u16* xk_lo = (u16*)(ws + 24 * MB);
    u16* xv_hi = (u16*)(ws + 32 * MB);
    u16* xv_lo = (u16*)(ws + 40 * MB);
    u16* wq_hi = (u16*)(ws + 48 * MB);
    u16* wq_lo = (u16*)(ws + 50 * MB);
    u16* wk_hi = (u16*)(ws + 52 * MB);
    u16* wk_lo = (u16*)(ws + 54 * MB);
    u16* wv_hi = (u16*)(ws + 56 * MB);
    u16* wv_lo = (u16*)(ws + 58 * MB);
    u16* qh    = (u16*)(ws + 60 * MB);
    u16* kh    = (u16*)(ws + 68 * MB);
    u16* vt    = (u16*)(ws + 76 * MB);

    SplitArgs sx;
    sx.src[0] = q;  sx.src[1] = k;  sx.src[2] = v;
    sx.hi[0] = xq_hi; sx.hi[1] = xk_hi; sx.hi[2] = xv_hi;
    sx.lo[0] = xq_lo; sx.lo[1] = xk_lo; sx.lo[2] = xv_lo;
    sx.n4 = in_sizes[0] / 4;
    split_kernel<<<dim3(2048, 3), 256, 0, stream>>>(sx);

    SplitArgs sw;
    sw.src[0] = Wq; sw.src[1] = Wk; sw.src[2] = Wv;
    sw.hi[0] = wq_hi; sw.hi[1] = wk_hi; sw.hi[2] = wv_hi;
    sw.lo[0] = wq_lo; sw.lo[1] = wk_lo; sw.lo[2] = wv_lo;
    sw.n4 = in_sizes[3] / 4;
    split_kernel<<<dim3(1024, 3), 256, 0, stream>>>(sw);

    ProjArgs pa;
    pa.xhi[0] = xq_hi; pa.xhi[1] = xk_hi; pa.xhi[2] = xv_hi;
    pa.xlo[0] = xq_lo; pa.xlo[1] = xk_lo; pa.xlo[2] = xv_lo;
    pa.whi[0] = wq_hi; pa.whi[1] = wk_hi; pa.whi[2] = wv_hi;
    pa.wlo[0] = wq_lo; pa.wlo[1] = wk_lo; pa.wlo[2] = wv_lo;
    pa.outq = qh; pa.outk = kh; pa.outvt = vt;
    proj_kernel<<<dim3(32, 8, 3), 256, 0, stream>>>(pa);

    attn_kernel<<<dim3(512), 512, 0, stream>>>(qh, kh, vt, (float*)d_out);
}

// Round 4
// 174.083 us; speedup vs baseline: 2.1698x; 1.2250x over previous
//
#include <hip/hip_runtime.h>
#include <hip/hip_bf16.h>
#include <stdint.h>

typedef unsigned short u16;
typedef __attribute__((ext_vector_type(8))) short bf16x8;
typedef __attribute__((ext_vector_type(4))) float f32x4;
typedef __attribute__((ext_vector_type(4))) u16 u16x4;
typedef __attribute__((ext_vector_type(4))) float f4v;

#define DEV __device__ __forceinline__

DEV u16 f2bf(float x) {
    union { float f; uint32_t u; } v; v.f = x;
    uint32_t r = v.u + 0x7FFF + ((v.u >> 16) & 1);
    return (u16)(r >> 16);
}
DEV float bf2f(u16 b) {
    union { uint32_t u; float f; } v; v.u = ((uint32_t)b) << 16;
    return v.f;
}

DEV f32x4 mfma16(bf16x8 a, bf16x8 b, f32x4 c) {
    return __builtin_amdgcn_mfma_f32_16x16x32_bf16(a, b, c, 0, 0, 0);
}

DEV void gld_lds16(const u16* g, u16* lds) {
    __builtin_amdgcn_global_load_lds(
        (const __attribute__((address_space(1))) void*)g,
        (__attribute__((address_space(3))) void*)lds, 16, 0, 0);
}

#define VMCNT2 asm volatile("s_waitcnt vmcnt(2)" ::: "memory")
#define VMCNT0 asm volatile("s_waitcnt vmcnt(0)" ::: "memory")
#define BAR() __builtin_amdgcn_s_barrier()

// ---------------- Pass A: fp32 -> bf16 hi/lo split ----------------
struct SplitArgs {
    const float* src[3];
    u16* hi[3];
    u16* lo[3];
    int n4;
};

__global__ __launch_bounds__(256) void split_kernel(SplitArgs a) {
    const int z = blockIdx.y;
    const f4v* __restrict__ src = (const f4v*)a.src[z];
    u16x4* __restrict__ hi = (u16x4*)a.hi[z];
    u16x4* __restrict__ lo = (u16x4*)a.lo[z];
    int i = blockIdx.x * blockDim.x + threadIdx.x;
    const int stride = gridDim.x * blockDim.x;
    for (; i < a.n4; i += stride) {
        f4v x = src[i];
        u16x4 h, l;
#pragma unroll
        for (int c = 0; c < 4; ++c) {
            float xv = x[c];
            u16 hb = f2bf(xv);
            float r = xv - bf2f(hb);
            h[c] = hb;
            l[c] = f2bf(r);
        }
        hi[i] = h;
        lo[i] = l;
    }
}

// ---------------- Pass B: projections — 256x256 tile, 8-wave, 8-phase ----------------
// A-matrix rows x B-matrix rows, both row-major [rows][K=1024], D[a][b] = sum A[a].B[b].
// z<2 : A = W-side (1024 rows, output-e), B = X-side (4096 rows) -> qh/kh [n][s][dk]
// z==2: A = X-side (4096 rows, output-m), B = W-side (1024 rows) -> vt [n][dk][s]
// 3 hi/lo terms chained into one 48-K-tile loop (BK=64 per tile).
struct ProjArgs {
    const u16* xhi[3];
    const u16* xlo[3];
    const u16* whi[3];
    const u16* wlo[3];
    u16* outq;
    u16* outk;
    u16* outvt;
};

__global__ __launch_bounds__(512, 2) void proj_kernel(ProjArgs args) {
    // [buf][ A: 256x64 (16384) | B: 256x64 (16384) ] elems, XOR-swizzled slots
    __shared__ u16 lds[2][32768];

    const int tid = threadIdx.x;
    const int w = tid >> 6, l = tid & 63;
    const int fr = l & 15, fg = l >> 4;
    const int wa = w >> 2, wb = w & 3;

    // bijective XCD swizzle (192 % 8 == 0): XCD x gets contiguous chunk of 24
    const int b0 = blockIdx.x;
    const int swz = (b0 & 7) * 24 + (b0 >> 3);
    const int z = swz >> 6;
    const int r = swz & 63;

    int ta, tb;
    const u16 *A0, *A1, *A2, *B0, *B1, *B2;
    if (z < 2) {
        ta = r & 3; tb = r >> 2;
        const u16* Wh = args.whi[z]; const u16* Wl = args.wlo[z];
        const u16* Xh = args.xhi[z]; const u16* Xl = args.xlo[z];
        A0 = Wh; A1 = Wl; A2 = Wh;
        B0 = Xh; B1 = Xh; B2 = Xl;
    } else {
        ta = r >> 2; tb = r & 3;
        const u16* Xh = args.xhi[2]; const u16* Xl = args.xlo[2];
        const u16* Wh = args.whi[2]; const u16* Wl = args.wlo[2];
        A0 = Xh; A1 = Xh; A2 = Xl;
        B0 = Wh; B1 = Wl; B2 = Wh;
    }

    // staging geometry: thread -> (row-in-64-block, swizzled source col)
    const int s_r = tid >> 3;                          // 0..63
    const int s_c = (((tid & 7) ^ (s_r & 7)) << 3);    // elem col (pre-swizzled source)
    const size_t aoff = (size_t)(ta * 256 + s_r) * 1024 + s_c;
    const size_t boff = (size_t)(tb * 256 + s_r) * 1024 + s_c;

    // read-side lane constants
    const int abase = (wa * 128 + fr) * 64;
    const int bbase = 16384 + (wb * 64 + fr) * 64;
    const int sl0 = ((fg) ^ (fr & 7)) << 3;        // kk=0 swizzled slot
    const int sl1 = ((4 + fg) ^ (fr & 7)) << 3;    // kk=1

    f32x4 acc[8][4];
#pragma unroll
    for (int mi = 0; mi < 8; ++mi)
#pragma unroll
        for (int ni = 0; ni < 4; ++ni)
            acc[mi][ni] = (f32x4){0.f, 0.f, 0.f, 0.f};

#define STAGE2(SRC, OFFBASE, REGION, HALF, BUFN, KTN)                               \
    do {                                                                            \
        _Pragma("unroll")                                                           \
        for (int j = 0; j < 2; ++j) {                                               \
            gld_lds16((SRC) + (OFFBASE) + (size_t)((HALF) * 128 + j * 64) * 1024    \
                           + (size_t)(KTN) * 64,                                    \
                      &lds[BUFN][(REGION) + (HALF) * 8192 + j * 4096 + w * 512]);   \
        }                                                                           \
    } while (0)

    // prologue: stage tile 0 (term 0, kt 0) into buf 0
#pragma unroll
    for (int h = 0; h < 2; ++h) {
#pragma unroll
        for (int j = 0; j < 2; ++j) {
            gld_lds16(A0 + aoff + (size_t)(h * 128 + j * 64) * 1024,
                      &lds[0][h * 8192 + j * 4096 + w * 512]);
            gld_lds16(B0 + boff + (size_t)(h * 128 + j * 64) * 1024,
                      &lds[0][16384 + h * 8192 + j * 4096 + w * 512]);
        }
    }

#define PHASE(MQ0, STAGECALL)                                                       \
    do {                                                                            \
        if (more) STAGECALL;                                                        \
        bf16x8 p00 = *(const bf16x8*)&Lb[abase + (MQ0) * 1024 + sl0];               \
        bf16x8 p01 = *(const bf16x8*)&Lb[abase + (MQ0) * 1024 + sl1];               \
        bf16x8 p10 = *(const bf16x8*)&Lb[abase + (MQ0 + 1) * 1024 + sl0];           \
        bf16x8 p11 = *(const bf16x8*)&Lb[abase + (MQ0 + 1) * 1024 + sl1];           \
        BAR();                                                                      \
        __builtin_amdgcn_s_setprio(1);                                              \
        _Pragma("unroll")                                                           \
        for (int ni = 0; ni < 4; ++ni) {                                            \
            acc[MQ0][ni] = mfma16(p00, Bf0[ni], acc[MQ0][ni]);                      \
            acc[MQ0][ni] = mfma16(p01, Bf1[ni], acc[MQ0][ni]);                      \
            acc[MQ0 + 1][ni] = mfma16(p10, Bf0[ni], acc[MQ0 + 1][ni]);              \
            acc[MQ0 + 1][ni] = mfma16(p11, Bf1[ni], acc[MQ0 + 1][ni]);              \
        }                                                                           \
        __builtin_amdgcn_s_setprio(0);                                              \
        BAR();                                                                      \
    } while (0)

#pragma unroll 1
    for (int t = 0; t < 48; ++t) {
        const int buf = t & 1;
        const int nbuf = buf ^ 1;
        const int tn = t + 1;
        const bool more = (tn < 48);
        const int termn = tn >> 4;
        const int ktn = tn & 15;
        const u16* An = (termn == 0) ? A0 : (termn == 1) ? A1 : A2;
        const u16* Bn = (termn == 0) ? B0 : (termn == 1) ? B1 : B2;
        const u16* Lb = &lds[buf][0];

        bf16x8 Bf0[4], Bf1[4];

        // ---- phase 0: boundary sync + A rows mq 0,1 + all B-frags ----
        if (more) STAGE2(An, aoff, 0, 0, nbuf, ktn);
        if (more) { VMCNT2; } else { VMCNT0; }
        BAR();
        {
            bf16x8 a00 = *(const bf16x8*)&Lb[abase + sl0];
            bf16x8 a01 = *(const bf16x8*)&Lb[abase + sl1];
            bf16x8 a10 = *(const bf16x8*)&Lb[abase + 1024 + sl0];
            bf16x8 a11 = *(const bf16x8*)&Lb[abase + 1024 + sl1];
#pragma unroll
            for (int ni = 0; ni < 4; ++ni) {
                Bf0[ni] = *(const bf16x8*)&Lb[bbase + ni * 1024 + sl0];
                Bf1[ni] = *(const bf16x8*)&Lb[bbase + ni * 1024 + sl1];
            }
            BAR();
            __builtin_amdgcn_s_setprio(1);
#pragma unroll
            for (int ni = 0; ni < 4; ++ni) {
                acc[0][ni] = mfma16(a00, Bf0[ni], acc[0][ni]);
                acc[0][ni] = mfma16(a01, Bf1[ni], acc[0][ni]);
                acc[1][ni] = mfma16(a10, Bf0[ni], acc[1][ni]);
                acc[1][ni] = mfma16(a11, Bf1[ni], acc[1][ni]);
            }
            __builtin_amdgcn_s_setprio(0);
            BAR();
        }
        // ---- phases 1..3 ----
        PHASE(2, STAGE2(An, aoff, 0, 1, nbuf, ktn));
        PHASE(4, STAGE2(Bn, boff, 16384, 0, nbuf, ktn));
        PHASE(6, STAGE2(Bn, boff, 16384, 1, nbuf, ktn));
    }
#undef PHASE
#undef STAGE2

    // ---- epilogue ----
    if (z < 2) {
        u16* outp = (z == 0) ? args.outq : args.outk;
#pragma unroll
        for (int mq = 0; mq < 8; ++mq) {
#pragma unroll
            for (int ni = 0; ni < 4; ++ni) {
                const int e0 = ta * 256 + wa * 128 + mq * 16 + fg * 4;
                const int m = tb * 256 + wb * 64 + ni * 16 + fr;
                const int n = (m >> 11) * 16 + (e0 >> 6);
                const int s = m & 2047;
                u16x4 pk;
#pragma unroll
                for (int rr = 0; rr < 4; ++rr) pk[rr] = f2bf(acc[mq][ni][rr]);
                *(u16x4*)&outp[((size_t)(n * 2048 + s)) * 64 + (e0 & 63)] = pk;
            }
        }
    } else {
        u16* outp = args.outvt;
#pragma unroll
        for (int mq = 0; mq < 8; ++mq) {
#pragma unroll
            for (int ni = 0; ni < 4; ++ni) {
                const int m0 = ta * 256 + wa * 128 + mq * 16 + fg * 4;
                const int e = tb * 256 + wb * 64 + ni * 16 + fr;
                const int n = (m0 >> 11) * 16 + (e >> 6);
                u16x4 pk;
#pragma unroll
                for (int rr = 0; rr < 4; ++rr) pk[rr] = f2bf(acc[mq][ni][rr]);
                *(u16x4*)&outp[((size_t)(n * 64 + (e & 63))) * 2048 + (m0 & 2047)] = pk;
            }
        }
    }
}

// ---------------- Pass C: flash attention, LDS-staged, double-buffered ----------------
__global__ __launch_bounds__(512, 4) void attn_kernel(const u16* __restrict__ qh,
                                                      const u16* __restrict__ kh,
                                                      const u16* __restrict__ vt,
                                                      float* __restrict__ out) {
    __shared__ u16 lds[2][16384];

    const int tid = threadIdx.x;
    const int w = tid >> 6, l = tid & 63;
    const int fr = l & 15, fg = l >> 4;

    const int b = blockIdx.x;
    const int n = (b & 7) * 4 + ((b >> 3) >> 4);
    const int qt = (b >> 3) & 15;
    const int qbase = qt * 128 + w * 16;
    const float cs = 0.125f * 1.44269504088896f;

    const u16* khn = kh + (size_t)n * 2048 * 64;
    const u16* vtn = vt + (size_t)n * 64 * 2048;

    const u16* qrow = qh + ((size_t)n * 2048 + qbase + fr) * 64;
    bf16x8 aq0 = *(const bf16x8*)(qrow + fg * 8);
    bf16x8 aq1 = *(const bf16x8*)(qrow + 32 + fg * 8);

    const int krow_s = tid >> 2;
    const int kcol_s = (tid & 3) * 16;
    const int kg_s = ((tid >> 2) & 3) + 4 * ((tid >> 5) & 1);
    const int kws0 = ((((tid & 3) * 2 + 0) + kg_s) & 7) * 8;
    const int kws1 = ((((tid & 3) * 2 + 1) + kg_s) & 7) * 8;
    const int vrow_s = tid >> 3;
    const int vcol_s = (tid & 7) * 16;
    const int vg_s = (tid >> 3) & 7;
    const int vws0 = ((((tid & 7) * 2 + 0) + vg_s) & 15) * 8;
    const int vws1 = ((((tid & 7) * 2 + 1) + vg_s) & 15) * 8;

    const int rbase = ((fr >> 2) << 3) + (fr & 3);
    const int kg_r = (fr & 3) + 4 * ((fr >> 2) & 1);
    const int ksl0 = (((fg + 0) + kg_r) & 7) * 8;
    const int ksl1 = (((fg + 4) + kg_r) & 7) * 8;
    const int vg_r = fr & 7;

    f32x4 acc[4];
#pragma unroll
    for (int dc = 0; dc < 4; ++dc) acc[dc] = (f32x4){0.f, 0.f, 0.f, 0.f};
    float mrun = -INFINITY;
    float lrun = 0.f;

    bf16x8 kr0, kr1, vr0, vr1;

#define STAGE_LOAD(kb_) do {                                                       \
        const u16* ksrc = khn + ((size_t)((kb_) * 128 + krow_s)) * 64 + kcol_s;    \
        kr0 = *(const bf16x8*)(ksrc);                                              \
        kr1 = *(const bf16x8*)(ksrc + 8);                                          \
        const u16* vsrc = vtn + (size_t)vrow_s * 2048 + (kb_) * 128 + vcol_s;      \
        vr0 = *(const bf16x8*)(vsrc);                                              \
        vr1 = *(const bf16x8*)(vsrc + 8);                                          \
    } while (0)

#define STAGE_WRITE(buf_) do {                                                     \
        u16* kp = &lds[buf_][0];                                                   \
        *(bf16x8*)&kp[krow_s * 64 + kws0] = kr0;                                   \
        *(bf16x8*)&kp[krow_s * 64 + kws1] = kr1;                                   \
        u16* vp = &lds[buf_][8192];                                                \
        *(bf16x8*)&vp[vrow_s * 128 + vws0] = vr0;                                  \
        *(bf16x8*)&vp[vrow_s * 128 + vws1] = vr1;                                  \
    } while (0)

    STAGE_LOAD(0);
    STAGE_WRITE(0);
    STAGE_LOAD(1);
    __syncthreads();

    for (int kb = 0; kb < 16; ++kb) {
        const int cur = kb & 1;
        const u16* Kb = &lds[cur][0];
        const u16* Vb = &lds[cur][8192];

        f32x4 sf[8];
#pragma unroll
        for (int c = 0; c < 8; ++c) {
            const int rr = ((c >> 1) << 5) + ((c & 1) << 2) + rbase;
            f32x4 s = (f32x4){0.f, 0.f, 0.f, 0.f};
            s = mfma16(*(const bf16x8*)&Kb[rr * 64 + ksl0], aq0, s);
            s = mfma16(*(const bf16x8*)&Kb[rr * 64 + ksl1], aq1, s);
            sf[c] = s;
        }

        f32x4 cmv = sf[0];
#pragma unroll
        for (int c = 1; c < 8; ++c)
#pragma unroll
            for (int rr = 0; rr < 4; ++rr) cmv[rr] = fmaxf(cmv[rr], sf[c][rr]);
        float cm = fmaxf(fmaxf(cmv[0], cmv[1]), fmaxf(cmv[2], cmv[3]));
        cm = fmaxf(cm, __shfl_xor(cm, 16, 64));
        cm = fmaxf(cm, __shfl_xor(cm, 32, 64));

        if (__any(cm > mrun)) {
            float mnew = fmaxf(mrun, cm);
            float sc = exp2f(cs * (mrun - mnew));
            mrun = mnew;
            lrun *= sc;
            float scq[4];
#pragma unroll
            for (int rr = 0; rr < 4; ++rr) scq[rr] = __shfl(sc, fg * 4 + rr, 64);
#pragma unroll
            for (int dc = 0; dc < 4; ++dc)
#pragma unroll
                for (int rr = 0; rr < 4; ++rr) acc[dc][rr] *= scq[rr];
        }

        const float negm = -cs * mrun;
        f32x4 psv = (f32x4){0.f, 0.f, 0.f, 0.f};
#pragma unroll
        for (int c = 0; c < 8; ++c) {
            f32x4 p;
#pragma unroll
            for (int rr = 0; rr < 4; ++rr) p[rr] = exp2f(fmaf(cs, sf[c][rr], negm));
            psv += p;
            sf[c] = p;
        }
        lrun += (psv[0] + psv[1]) + (psv[2] + psv[3]);

#pragma unroll
        for (int pw = 0; pw < 4; ++pw) {
            union { bf16x8 v; uint32_t u[4]; } ap;
#pragma unroll
            for (int q2 = 0; q2 < 4; ++q2) {
                float lo = sf[2 * pw + (q2 >> 1)][(q2 & 1) * 2 + 0];
                float hi = sf[2 * pw + (q2 >> 1)][(q2 & 1) * 2 + 1];
                asm("v_cvt_pk_bf16_f32 %0, %1, %2" : "=v"(ap.u[q2]) : "v"(lo), "v"(hi));
            }
#pragma unroll
            for (int dc = 0; dc < 4; ++dc) {
                const int vsl = (((pw * 4 + fg) + vg_r) & 15) * 8;
                acc[dc] = mfma16(ap.v, *(const bf16x8*)&Vb[(dc * 16 + fr) * 128 + vsl],
                                 acc[dc]);
            }
        }

        if (kb < 15) {
            __syncthreads();
            STAGE_WRITE(cur ^ 1);
            if (kb < 14) STAGE_LOAD(kb + 2);
            __syncthreads();
        }
    }

    lrun += __shfl_xor(lrun, 16, 64);
    lrun += __shfl_xor(lrun, 32, 64);
    float inv = 1.f / lrun;
    float invq[4];
#pragma unroll
    for (int rr = 0; rr < 4; ++rr) invq[rr] = __shfl(inv, fg * 4 + rr, 64);

    const int bq = n & 1;
    const int col0 = (n >> 1) * 64;
    float* orow = out + ((size_t)bq * 2048 + qbase + fg * 4) * 1024 + col0;
#pragma unroll
    for (int dc = 0; dc < 4; ++dc)
#pragma unroll
        for (int rr = 0; rr < 4; ++rr)
            orow[(size_t)rr * 1024 + dc * 16 + fr] = acc[dc][rr] * invq[rr];
#undef STAGE_LOAD
#undef STAGE_WRITE
}

// ---------------- launch ----------------
extern "C" void kernel_launch(void* const* d_in, const int* in_sizes, int n_in,
                              void* d_out, int out_size, void* d_ws, size_t ws_size,
                              hipStream_t stream) {
    (void)n_in; (void)out_size; (void)ws_size;
    const float* q  = (const float*)d_in[0];
    const float* k  = (const float*)d_in[1];
    const float* v  = (const float*)d_in[2];
    const float* Wq = (const float*)d_in[3];
    const float* Wk = (const float*)d_in[4];
    const float* Wv = (const float*)d_in[5];

    uint8_t* ws = (uint8_t*)d_ws;
    const size_t MB = 1024ull * 1024ull;
    u16* xq_hi = (u16*)(ws + 0 * MB);
    u16* xq_lo = (u16*)(ws + 8 * MB);
    u16* xk_hi = (u16*)(ws + 16 * MB);
    u16* xk_lo = (u16*)(ws + 24 * MB);
    u16* xv_hi = (u16*)(ws + 32 * MB);
    u16* xv_lo = (u16*)(ws + 40 * MB);
    u16* wq_hi = (u16*)(ws + 48 * MB);
    u16* wq_lo = (u16*)(ws + 50 * MB);
    u16* wk_hi = (u16*)(ws + 52 * MB);
    u16* wk_lo = (u16*)(ws + 54 * MB);
    u16* wv_hi = (u16*)(ws + 56 * MB);
    u16* wv_lo = (u16*)(ws + 58 * MB);
    u16* qh    = (u16*)(ws + 60 * MB);
    u16* kh    = (u16*)(ws + 68 * MB);
    u16* vt    = (u16*)(ws + 76 * MB);

    SplitArgs sx;
    sx.src[0] = q;  sx.src[1] = k;  sx.src[2] = v;
    sx.hi[0] = xq_hi; sx.hi[1] = xk_hi; sx.hi[2] = xv_hi;
    sx.lo[0] = xq_lo; sx.lo[1] = xk_lo; sx.lo[2] = xv_lo;
    sx.n4 = in_sizes[0] / 4;
    split_kernel<<<dim3(2048, 3), 256, 0, stream>>>(sx);

    SplitArgs sw;
    sw.src[0] = Wq; sw.src[1] = Wk; sw.src[2] = Wv;
    sw.hi[0] = wq_hi; sw.hi[1] = wk_hi; sw.hi[2] = wv_hi;
    sw.lo[0] = wq_lo; sw.lo[1] = wk_lo; sw.lo[2] = wv_lo;
    sw.n4 = in_sizes[3] / 4;
    split_kernel<<<dim3(1024, 3), 256, 0, stream>>>(sw);

    ProjArgs pa;
    pa.xhi[0] = xq_hi; pa.xhi[1] = xk_hi; pa.xhi[2] = xv_hi;
    pa.xlo[0] = xq_lo; pa.xlo[1] = xk_lo; pa.xlo[2] = xv_lo;
    pa.whi[0] = wq_hi; pa.whi[1] = wk_hi; pa.whi[2] = wv_hi;
    pa.wlo[0] = wq_lo; pa.wlo[1] = wk_lo; pa.wlo[2] = wv_lo;
    pa.outq = qh; pa.outk = kh; pa.outvt = vt;
    proj_kernel<<<dim3(192), 512, 0, stream>>>(pa);

    attn_kernel<<<dim3(512), 512, 0, stream>>>(qh, kh, vt, (float*)d_out);
}

// Round 5
// 147.795 us; speedup vs baseline: 2.5557x; 1.1779x over previous
//
#include <hip/hip_runtime.h>
#include <hip/hip_bf16.h>
#include <stdint.h>

typedef unsigned short u16;
typedef __attribute__((ext_vector_type(8))) short bf16x8;
typedef __attribute__((ext_vector_type(8))) _Float16 f16x8;
typedef __attribute__((ext_vector_type(4))) float f32x4;
typedef __attribute__((ext_vector_type(4))) u16 u16x4;
typedef __attribute__((ext_vector_type(4))) float f4v;

#define DEV __device__ __forceinline__

DEV u16 f2bf(float x) {
    union { float f; uint32_t u; } v; v.f = x;
    uint32_t r = v.u + 0x7FFF + ((v.u >> 16) & 1);
    return (u16)(r >> 16);
}

DEV f32x4 mfma16(bf16x8 a, bf16x8 b, f32x4 c) {
    return __builtin_amdgcn_mfma_f32_16x16x32_bf16(a, b, c, 0, 0, 0);
}
DEV f32x4 mfma16h(f16x8 a, f16x8 b, f32x4 c) {
    return __builtin_amdgcn_mfma_f32_16x16x32_f16(a, b, c, 0, 0, 0);
}

DEV void gld_lds16(const u16* g, u16* lds) {
    __builtin_amdgcn_global_load_lds(
        (const __attribute__((address_space(1))) void*)g,
        (__attribute__((address_space(3))) void*)lds, 16, 0, 0);
}

#define VMCNT2 asm volatile("s_waitcnt vmcnt(2)" ::: "memory")
#define VMCNT0 asm volatile("s_waitcnt vmcnt(0)" ::: "memory")
#define BAR() __builtin_amdgcn_s_barrier()

DEV u16 h2u(_Float16 h) { union { _Float16 h; u16 u; } v; v.h = h; return v.u; }

// ---------------- Pass A1: X fp32 -> fp16 hi/lo split ----------------
struct SplitArgs {
    const float* src[3];
    u16* hi[3];
    u16* lo[3];
    int n4;
};

__global__ __launch_bounds__(256) void splitx_kernel(SplitArgs a) {
    const int z = blockIdx.y;
    const f4v* __restrict__ src = (const f4v*)a.src[z];
    u16x4* __restrict__ hi = (u16x4*)a.hi[z];
    u16x4* __restrict__ lo = (u16x4*)a.lo[z];
    int i = blockIdx.x * blockDim.x + threadIdx.x;
    const int stride = gridDim.x * blockDim.x;
    for (; i < a.n4; i += stride) {
        f4v x = src[i];
        u16x4 h, l;
#pragma unroll
        for (int c = 0; c < 4; ++c) {
            float xv = x[c];
            _Float16 hb = (_Float16)xv;
            float r = xv - (float)hb;
            h[c] = h2u(hb);
            l[c] = h2u((_Float16)r);
        }
        hi[i] = h;
        lo[i] = l;
    }
}

// ---------------- Pass A2: W fp32 -> fp16 cast ----------------
struct CastArgs {
    const float* src[3];
    u16* dst[3];
    int n4;
};

__global__ __launch_bounds__(256) void castw_kernel(CastArgs a) {
    const int z = blockIdx.y;
    const f4v* __restrict__ src = (const f4v*)a.src[z];
    u16x4* __restrict__ dst = (u16x4*)a.dst[z];
    int i = blockIdx.x * blockDim.x + threadIdx.x;
    const int stride = gridDim.x * blockDim.x;
    for (; i < a.n4; i += stride) {
        f4v x = src[i];
        u16x4 d;
#pragma unroll
        for (int c = 0; c < 4; ++c) d[c] = h2u((_Float16)x[c]);
        dst[i] = d;
    }
}

// ---------------- Pass B: projections — 256x256 tile, 8-wave, 8-phase, fp16 2-term ----------------
// D[a][b] = sum_d A[a][d]*B[b][d], both row-major [rows][1024] fp16.
// z<2 : A = Wf (1024 rows, output-e), B = X-side -> qh/kh [n][s][dk] (bf16)
// z==2: A = X-side (4096 rows, output-m), B = Wf -> vt [n][dk][s] (bf16)
// terms: t<16 uses (A0,B0); t>=16 uses (A1,B1).
struct ProjArgs {
    const u16* xhi[3];
    const u16* xlo[3];
    const u16* wf[3];
    u16* outq;
    u16* outk;
    u16* outvt;
};

__global__ __launch_bounds__(512, 2) void proj_kernel(ProjArgs args) {
    __shared__ u16 lds[2][32768];

    const int tid = threadIdx.x;
    const int w = tid >> 6, l = tid & 63;
    const int fr = l & 15, fg = l >> 4;
    const int wa = w >> 2, wb = w & 3;

    // bijective XCD swizzle (192 % 8 == 0)
    const int b0 = blockIdx.x;
    const int swz = (b0 & 7) * 24 + (b0 >> 3);
    const int z = swz >> 6;
    const int r = swz & 63;

    int ta, tb;
    const u16 *A0, *A1, *B0, *B1;
    if (z < 2) {
        ta = r & 3; tb = r >> 2;
        A0 = args.wf[z]; A1 = args.wf[z];
        B0 = args.xhi[z]; B1 = args.xlo[z];
    } else {
        ta = r >> 2; tb = r & 3;
        A0 = args.xhi[2]; A1 = args.xlo[2];
        B0 = args.wf[2]; B1 = args.wf[2];
    }

    const int s_r = tid >> 3;
    const int s_c = (((tid & 7) ^ (s_r & 7)) << 3);
    const size_t aoff = (size_t)(ta * 256 + s_r) * 1024 + s_c;
    const size_t boff = (size_t)(tb * 256 + s_r) * 1024 + s_c;

    const int abase = (wa * 128 + fr) * 64;
    const int bbase = 16384 + (wb * 64 + fr) * 64;
    const int sl0 = ((fg) ^ (fr & 7)) << 3;
    const int sl1 = ((4 + fg) ^ (fr & 7)) << 3;

    f32x4 acc[8][4];
#pragma unroll
    for (int mi = 0; mi < 8; ++mi)
#pragma unroll
        for (int ni = 0; ni < 4; ++ni)
            acc[mi][ni] = (f32x4){0.f, 0.f, 0.f, 0.f};

#define STAGE2(SRC, OFFBASE, REGION, HALF, BUFN, KTN)                               \
    do {                                                                            \
        _Pragma("unroll")                                                           \
        for (int j = 0; j < 2; ++j) {                                               \
            gld_lds16((SRC) + (OFFBASE) + (size_t)((HALF) * 128 + j * 64) * 1024    \
                           + (size_t)(KTN) * 64,                                    \
                      &lds[BUFN][(REGION) + (HALF) * 8192 + j * 4096 + w * 512]);   \
        }                                                                           \
    } while (0)

    // prologue: stage tile 0 (term 0, kt 0) into buf 0
#pragma unroll
    for (int h = 0; h < 2; ++h) {
#pragma unroll
        for (int j = 0; j < 2; ++j) {
            gld_lds16(A0 + aoff + (size_t)(h * 128 + j * 64) * 1024,
                      &lds[0][h * 8192 + j * 4096 + w * 512]);
            gld_lds16(B0 + boff + (size_t)(h * 128 + j * 64) * 1024,
                      &lds[0][16384 + h * 8192 + j * 4096 + w * 512]);
        }
    }

#define PHASE(MQ0, STAGECALL)                                                       \
    do {                                                                            \
        if (more) STAGECALL;                                                        \
        f16x8 p00 = *(const f16x8*)&Lb[abase + (MQ0) * 1024 + sl0];                 \
        f16x8 p01 = *(const f16x8*)&Lb[abase + (MQ0) * 1024 + sl1];                 \
        f16x8 p10 = *(const f16x8*)&Lb[abase + (MQ0 + 1) * 1024 + sl0];             \
        f16x8 p11 = *(const f16x8*)&Lb[abase + (MQ0 + 1) * 1024 + sl1];             \
        BAR();                                                                      \
        __builtin_amdgcn_s_setprio(1);                                              \
        _Pragma("unroll")                                                           \
        for (int ni = 0; ni < 4; ++ni) {                                            \
            acc[MQ0][ni] = mfma16h(p00, Bf0[ni], acc[MQ0][ni]);                     \
            acc[MQ0][ni] = mfma16h(p01, Bf1[ni], acc[MQ0][ni]);                     \
            acc[MQ0 + 1][ni] = mfma16h(p10, Bf0[ni], acc[MQ0 + 1][ni]);             \
            acc[MQ0 + 1][ni] = mfma16h(p11, Bf1[ni], acc[MQ0 + 1][ni]);             \
        }                                                                           \
        __builtin_amdgcn_s_setprio(0);                                              \
        BAR();                                                                      \
    } while (0)

#pragma unroll 1
    for (int t = 0; t < 32; ++t) {
        const int buf = t & 1;
        const int nbuf = buf ^ 1;
        const int tn = t + 1;
        const bool more = (tn < 32);
        const int termn = tn >> 4;
        const int ktn = tn & 15;
        const u16* An = termn ? A1 : A0;
        const u16* Bn = termn ? B1 : B0;
        const u16* Lb = &lds[buf][0];

        f16x8 Bf0[4], Bf1[4];

        // ---- phase 0: boundary sync + A rows mq 0,1 + all B-frags ----
        if (more) STAGE2(An, aoff, 0, 0, nbuf, ktn);
        if (more) { VMCNT2; } else { VMCNT0; }
        BAR();
        {
            f16x8 a00 = *(const f16x8*)&Lb[abase + sl0];
            f16x8 a01 = *(const f16x8*)&Lb[abase + sl1];
            f16x8 a10 = *(const f16x8*)&Lb[abase + 1024 + sl0];
            f16x8 a11 = *(const f16x8*)&Lb[abase + 1024 + sl1];
#pragma unroll
            for (int ni = 0; ni < 4; ++ni) {
                Bf0[ni] = *(const f16x8*)&Lb[bbase + ni * 1024 + sl0];
                Bf1[ni] = *(const f16x8*)&Lb[bbase + ni * 1024 + sl1];
            }
            BAR();
            __builtin_amdgcn_s_setprio(1);
#pragma unroll
            for (int ni = 0; ni < 4; ++ni) {
                acc[0][ni] = mfma16h(a00, Bf0[ni], acc[0][ni]);
                acc[0][ni] = mfma16h(a01, Bf1[ni], acc[0][ni]);
                acc[1][ni] = mfma16h(a10, Bf0[ni], acc[1][ni]);
                acc[1][ni] = mfma16h(a11, Bf1[ni], acc[1][ni]);
            }
            __builtin_amdgcn_s_setprio(0);
            BAR();
        }
        PHASE(2, STAGE2(An, aoff, 0, 1, nbuf, ktn));
        PHASE(4, STAGE2(Bn, boff, 16384, 0, nbuf, ktn));
        PHASE(6, STAGE2(Bn, boff, 16384, 1, nbuf, ktn));
    }
#undef PHASE
#undef STAGE2

    // ---- epilogue ----
    if (z < 2) {
        u16* outp = (z == 0) ? args.outq : args.outk;
#pragma unroll
        for (int mq = 0; mq < 8; ++mq) {
#pragma unroll
            for (int ni = 0; ni < 4; ++ni) {
                const int e0 = ta * 256 + wa * 128 + mq * 16 + fg * 4;
                const int m = tb * 256 + wb * 64 + ni * 16 + fr;
                const int n = (m >> 11) * 16 + (e0 >> 6);
                const int s = m & 2047;
                u16x4 pk;
#pragma unroll
                for (int rr = 0; rr < 4; ++rr) pk[rr] = f2bf(acc[mq][ni][rr]);
                *(u16x4*)&outp[((size_t)(n * 2048 + s)) * 64 + (e0 & 63)] = pk;
            }
        }
    } else {
        u16* outp = args.outvt;
#pragma unroll
        for (int mq = 0; mq < 8; ++mq) {
#pragma unroll
            for (int ni = 0; ni < 4; ++ni) {
                const int m0 = ta * 256 + wa * 128 + mq * 16 + fg * 4;
                const int e = tb * 256 + wb * 64 + ni * 16 + fr;
                const int n = (m0 >> 11) * 16 + (e >> 6);
                u16x4 pk;
#pragma unroll
                for (int rr = 0; rr < 4; ++rr) pk[rr] = f2bf(acc[mq][ni][rr]);
                *(u16x4*)&outp[((size_t)(n * 64 + (e & 63))) * 2048 + (m0 & 2047)] = pk;
            }
        }
    }
}

// ---------------- Pass C: flash attention, LDS-staged, double-buffered ----------------
__global__ __launch_bounds__(512, 4) void attn_kernel(const u16* __restrict__ qh,
                                                      const u16* __restrict__ kh,
                                                      const u16* __restrict__ vt,
                                                      float* __restrict__ out) {
    __shared__ u16 lds[2][16384];

    const int tid = threadIdx.x;
    const int w = tid >> 6, l = tid & 63;
    const int fr = l & 15, fg = l >> 4;

    const int b = blockIdx.x;
    const int n = (b & 7) * 4 + ((b >> 3) >> 4);
    const int qt = (b >> 3) & 15;
    const int qbase = qt * 128 + w * 16;
    const float cs = 0.125f * 1.44269504088896f;

    const u16* khn = kh + (size_t)n * 2048 * 64;
    const u16* vtn = vt + (size_t)n * 64 * 2048;

    const u16* qrow = qh + ((size_t)n * 2048 + qbase + fr) * 64;
    bf16x8 aq0 = *(const bf16x8*)(qrow + fg * 8);
    bf16x8 aq1 = *(const bf16x8*)(qrow + 32 + fg * 8);

    const int krow_s = tid >> 2;
    const int kcol_s = (tid & 3) * 16;
    const int kg_s = ((tid >> 2) & 3) + 4 * ((tid >> 5) & 1);
    const int kws0 = ((((tid & 3) * 2 + 0) + kg_s) & 7) * 8;
    const int kws1 = ((((tid & 3) * 2 + 1) + kg_s) & 7) * 8;
    const int vrow_s = tid >> 3;
    const int vcol_s = (tid & 7) * 16;
    const int vg_s = (tid >> 3) & 7;
    const int vws0 = ((((tid & 7) * 2 + 0) + vg_s) & 15) * 8;
    const int vws1 = ((((tid & 7) * 2 + 1) + vg_s) & 15) * 8;

    const int rbase = ((fr >> 2) << 3) + (fr & 3);
    const int kg_r = (fr & 3) + 4 * ((fr >> 2) & 1);
    const int ksl0 = (((fg + 0) + kg_r) & 7) * 8;
    const int ksl1 = (((fg + 4) + kg_r) & 7) * 8;
    const int vg_r = fr & 7;

    f32x4 acc[4];
#pragma unroll
    for (int dc = 0; dc < 4; ++dc) acc[dc] = (f32x4){0.f, 0.f, 0.f, 0.f};
    float mrun = -INFINITY;
    float lrun = 0.f;

    bf16x8 kr0, kr1, vr0, vr1;

#define STAGE_LOAD(kb_) do {                                                       \
        const u16* ksrc = khn + ((size_t)((kb_) * 128 + krow_s)) * 64 + kcol_s;    \
        kr0 = *(const bf16x8*)(ksrc);                                              \
        kr1 = *(const bf16x8*)(ksrc + 8);                                          \
        const u16* vsrc = vtn + (size_t)vrow_s * 2048 + (kb_) * 128 + vcol_s;      \
        vr0 = *(const bf16x8*)(vsrc);                                              \
        vr1 = *(const bf16x8*)(vsrc + 8);                                          \
    } while (0)

#define STAGE_WRITE(buf_) do {                                                     \
        u16* kp = &lds[buf_][0];                                                   \
        *(bf16x8*)&kp[krow_s * 64 + kws0] = kr0;                                   \
        *(bf16x8*)&kp[krow_s * 64 + kws1] = kr1;                                   \
        u16* vp = &lds[buf_][8192];                                                \
        *(bf16x8*)&vp[vrow_s * 128 + vws0] = vr0;                                  \
        *(bf16x8*)&vp[vrow_s * 128 + vws1] = vr1;                                  \
    } while (0)

    STAGE_LOAD(0);
    STAGE_WRITE(0);
    STAGE_LOAD(1);
    __syncthreads();

    for (int kb = 0; kb < 16; ++kb) {
        const int cur = kb & 1;
        const u16* Kb = &lds[cur][0];
        const u16* Vb = &lds[cur][8192];

        f32x4 sf[8];
#pragma unroll
        for (int c = 0; c < 8; ++c) {
            const int rr = ((c >> 1) << 5) + ((c & 1) << 2) + rbase;
            f32x4 s = (f32x4){0.f, 0.f, 0.f, 0.f};
            s = mfma16(*(const bf16x8*)&Kb[rr * 64 + ksl0], aq0, s);
            s = mfma16(*(const bf16x8*)&Kb[rr * 64 + ksl1], aq1, s);
            sf[c] = s;
        }

        f32x4 cmv = sf[0];
#pragma unroll
        for (int c = 1; c < 8; ++c)
#pragma unroll
            for (int rr = 0; rr < 4; ++rr) cmv[rr] = fmaxf(cmv[rr], sf[c][rr]);
        float cm = fmaxf(fmaxf(cmv[0], cmv[1]), fmaxf(cmv[2], cmv[3]));
        cm = fmaxf(cm, __shfl_xor(cm, 16, 64));
        cm = fmaxf(cm, __shfl_xor(cm, 32, 64));

        if (__any(cm > mrun)) {
            float mnew = fmaxf(mrun, cm);
            float sc = exp2f(cs * (mrun - mnew));
            mrun = mnew;
            lrun *= sc;
            float scq[4];
#pragma unroll
            for (int rr = 0; rr < 4; ++rr) scq[rr] = __shfl(sc, fg * 4 + rr, 64);
#pragma unroll
            for (int dc = 0; dc < 4; ++dc)
#pragma unroll
                for (int rr = 0; rr < 4; ++rr) acc[dc][rr] *= scq[rr];
        }

        const float negm = -cs * mrun;
        f32x4 psv = (f32x4){0.f, 0.f, 0.f, 0.f};
#pragma unroll
        for (int c = 0; c < 8; ++c) {
            f32x4 p;
#pragma unroll
            for (int rr = 0; rr < 4; ++rr) p[rr] = exp2f(fmaf(cs, sf[c][rr], negm));
            psv += p;
            sf[c] = p;
        }
        lrun += (psv[0] + psv[1]) + (psv[2] + psv[3]);

#pragma unroll
        for (int pw = 0; pw < 4; ++pw) {
            union { bf16x8 v; uint32_t u[4]; } ap;
#pragma unroll
            for (int q2 = 0; q2 < 4; ++q2) {
                float lo = sf[2 * pw + (q2 >> 1)][(q2 & 1) * 2 + 0];
                float hi = sf[2 * pw + (q2 >> 1)][(q2 & 1) * 2 + 1];
                asm("v_cvt_pk_bf16_f32 %0, %1, %2" : "=v"(ap.u[q2]) : "v"(lo), "v"(hi));
            }
#pragma unroll
            for (int dc = 0; dc < 4; ++dc) {
                const int vsl = (((pw * 4 + fg) + vg_r) & 15) * 8;
                acc[dc] = mfma16(ap.v, *(const bf16x8*)&Vb[(dc * 16 + fr) * 128 + vsl],
                                 acc[dc]);
            }
        }

        if (kb < 15) {
            __syncthreads();
            STAGE_WRITE(cur ^ 1);
            if (kb < 14) STAGE_LOAD(kb + 2);
            __syncthreads();
        }
    }

    lrun += __shfl_xor(lrun, 16, 64);
    lrun += __shfl_xor(lrun, 32, 64);
    float inv = 1.f / lrun;
    float invq[4];
#pragma unroll
    for (int rr = 0; rr < 4; ++rr) invq[rr] = __shfl(inv, fg * 4 + rr, 64);

    const int bq = n & 1;
    const int col0 = (n >> 1) * 64;
    float* orow = out + ((size_t)bq * 2048 + qbase + fg * 4) * 1024 + col0;
#pragma unroll
    for (int dc = 0; dc < 4; ++dc)
#pragma unroll
        for (int rr = 0; rr < 4; ++rr)
            orow[(size_t)rr * 1024 + dc * 16 + fr] = acc[dc][rr] * invq[rr];
#undef STAGE_LOAD
#undef STAGE_WRITE
}

// ---------------- launch ----------------
extern "C" void kernel_launch(void* const* d_in, const int* in_sizes, int n_in,
                              void* d_out, int out_size, void* d_ws, size_t ws_size,
                              hipStream_t stream) {
    (void)n_in; (void)out_size; (void)ws_size;
    const float* q  = (const float*)d_in[0];
    const float* k  = (const float*)d_in[1];
    const float* v  = (const float*)d_in[2];
    const float* Wq = (const float*)d_in[3];
    const float* Wk = (const float*)d_in[4];
    const float* Wv = (const float*)d_in[5];

    uint8_t* ws = (uint8_t*)d_ws;
    const size_t MB = 1024ull * 1024ull;
    u16* xq_hi = (u16*)(ws + 0 * MB);
    u16* xq_lo = (u16*)(ws + 8 * MB);
    u16* xk_hi = (u16*)(ws + 16 * MB);
    u16* xk_lo = (u16*)(ws + 24 * MB);
    u16* xv_hi = (u16*)(ws + 32 * MB);
    u16* xv_lo = (u16*)(ws + 40 * MB);
    u16* wq_f  = (u16*)(ws + 48 * MB);
    u16* wk_f  = (u16*)(ws + 50 * MB);
    u16* wv_f  = (u16*)(ws + 52 * MB);
    u16* qh    = (u16*)(ws + 54 * MB);
    u16* kh    = (u16*)(ws + 62 * MB);
    u16* vt    = (u16*)(ws + 70 * MB);

    SplitArgs sx;
    sx.src[0] = q;  sx.src[1] = k;  sx.src[2] = v;
    sx.hi[0] = xq_hi; sx.hi[1] = xk_hi; sx.hi[2] = xv_hi;
    sx.lo[0] = xq_lo; sx.lo[1] = xk_lo; sx.lo[2] = xv_lo;
    sx.n4 = in_sizes[0] / 4;
    splitx_kernel<<<dim3(2048, 3), 256, 0, stream>>>(sx);

    CastArgs cw;
    cw.src[0] = Wq; cw.src[1] = Wk; cw.src[2] = Wv;
    cw.dst[0] = wq_f; cw.dst[1] = wk_f; cw.dst[2] = wv_f;
    cw.n4 = in_sizes[3] / 4;
    castw_kernel<<<dim3(512, 3), 256, 0, stream>>>(cw);

    ProjArgs pa;
    pa.xhi[0] = xq_hi; pa.xhi[1] = xk_hi; pa.xhi[2] = xv_hi;
    pa.xlo[0] = xq_lo; pa.xlo[1] = xk_lo; pa.xlo[2] = xv_lo;
    pa.wf[0] = wq_f; pa.wf[1] = wk_f; pa.wf[2] = wv_f;
    pa.outq = qh; pa.outk = kh; pa.outvt = vt;
    proj_kernel<<<dim3(192), 512, 0, stream>>>(pa);

    attn_kernel<<<dim3(512), 512, 0, stream>>>(qh, kh, vt, (float*)d_out);
}

// Round 6
// 133.186 us; speedup vs baseline: 2.8361x; 1.1097x over previous
//
#include <hip/hip_runtime.h>
#include <hip/hip_bf16.h>
#include <stdint.h>

typedef unsigned short u16;
typedef __attribute__((ext_vector_type(8))) short bf16x8;
typedef __attribute__((ext_vector_type(8))) _Float16 f16x8;
typedef __attribute__((ext_vector_type(4))) float f32x4;
typedef __attribute__((ext_vector_type(4))) u16 u16x4;
typedef __attribute__((ext_vector_type(4))) float f4v;

#define DEV __device__ __forceinline__

DEV u16 f2bf(float x) {
    union { float f; uint32_t u; } v; v.f = x;
    uint32_t r = v.u + 0x7FFF + ((v.u >> 16) & 1);
    return (u16)(r >> 16);
}

DEV float fexp2(float x) {
    float r;
    asm("v_exp_f32 %0, %1" : "=v"(r) : "v"(x));
    return r;
}

DEV f32x4 mfma16(bf16x8 a, bf16x8 b, f32x4 c) {
    return __builtin_amdgcn_mfma_f32_16x16x32_bf16(a, b, c, 0, 0, 0);
}
DEV f32x4 mfma16h(f16x8 a, f16x8 b, f32x4 c) {
    return __builtin_amdgcn_mfma_f32_16x16x32_f16(a, b, c, 0, 0, 0);
}

DEV void gld_lds16(const u16* g, u16* lds) {
    __builtin_amdgcn_global_load_lds(
        (const __attribute__((address_space(1))) void*)g,
        (__attribute__((address_space(3))) void*)lds, 16, 0, 0);
}

#define VMCNT2 asm volatile("s_waitcnt vmcnt(2)" ::: "memory")
#define VMCNT0 asm volatile("s_waitcnt vmcnt(0)" ::: "memory")
#define BAR() __builtin_amdgcn_s_barrier()

DEV u16 h2u(_Float16 h) { union { _Float16 h; u16 u; } v; v.h = h; return v.u; }

// ---------------- Pass A1: X fp32 -> fp16 hi/lo split ----------------
struct SplitArgs {
    const float* src[3];
    u16* hi[3];
    u16* lo[3];
    int n4;
};

__global__ __launch_bounds__(256) void splitx_kernel(SplitArgs a) {
    const int z = blockIdx.y;
    const f4v* __restrict__ src = (const f4v*)a.src[z];
    u16x4* __restrict__ hi = (u16x4*)a.hi[z];
    u16x4* __restrict__ lo = (u16x4*)a.lo[z];
    int i = blockIdx.x * blockDim.x + threadIdx.x;
    const int stride = gridDim.x * blockDim.x;
    for (; i < a.n4; i += stride) {
        f4v x = src[i];
        u16x4 h, l;
#pragma unroll
        for (int c = 0; c < 4; ++c) {
            float xv = x[c];
            _Float16 hb = (_Float16)xv;
            float r = xv - (float)hb;
            h[c] = h2u(hb);
            l[c] = h2u((_Float16)r);
        }
        hi[i] = h;
        lo[i] = l;
    }
}

// ---------------- Pass A2: W fp32 -> fp16 cast ----------------
struct CastArgs {
    const float* src[3];
    u16* dst[3];
    int n4;
};

__global__ __launch_bounds__(256) void castw_kernel(CastArgs a) {
    const int z = blockIdx.y;
    const f4v* __restrict__ src = (const f4v*)a.src[z];
    u16x4* __restrict__ dst = (u16x4*)a.dst[z];
    int i = blockIdx.x * blockDim.x + threadIdx.x;
    const int stride = gridDim.x * blockDim.x;
    for (; i < a.n4; i += stride) {
        f4v x = src[i];
        u16x4 d;
#pragma unroll
        for (int c = 0; c < 4; ++c) d[c] = h2u((_Float16)x[c]);
        dst[i] = d;
    }
}

// ---------------- Pass B: projections — 256x256 tile, 8-wave, 8-phase, fp16 2-term ----------------
struct ProjArgs {
    const u16* xhi[3];
    const u16* xlo[3];
    const u16* wf[3];
    u16* outq;
    u16* outk;
    u16* outvt;
};

__global__ __launch_bounds__(512, 2) void proj_kernel(ProjArgs args) {
    __shared__ u16 lds[2][32768];

    const int tid = threadIdx.x;
    const int w = tid >> 6, l = tid & 63;
    const int fr = l & 15, fg = l >> 4;
    const int wa = w >> 2, wb = w & 3;

    const int b0 = blockIdx.x;
    const int swz = (b0 & 7) * 24 + (b0 >> 3);
    const int z = swz >> 6;
    const int r = swz & 63;

    int ta, tb;
    const u16 *A0, *A1, *B0, *B1;
    if (z < 2) {
        ta = r & 3; tb = r >> 2;
        A0 = args.wf[z]; A1 = args.wf[z];
        B0 = args.xhi[z]; B1 = args.xlo[z];
    } else {
        ta = r >> 2; tb = r & 3;
        A0 = args.xhi[2]; A1 = args.xlo[2];
        B0 = args.wf[2]; B1 = args.wf[2];
    }

    const int s_r = tid >> 3;
    const int s_c = (((tid & 7) ^ (s_r & 7)) << 3);
    const size_t aoff = (size_t)(ta * 256 + s_r) * 1024 + s_c;
    const size_t boff = (size_t)(tb * 256 + s_r) * 1024 + s_c;

    const int abase = (wa * 128 + fr) * 64;
    const int bbase = 16384 + (wb * 64 + fr) * 64;
    const int sl0 = ((fg) ^ (fr & 7)) << 3;
    const int sl1 = ((4 + fg) ^ (fr & 7)) << 3;

    f32x4 acc[8][4];
#pragma unroll
    for (int mi = 0; mi < 8; ++mi)
#pragma unroll
        for (int ni = 0; ni < 4; ++ni)
            acc[mi][ni] = (f32x4){0.f, 0.f, 0.f, 0.f};

#define STAGE2(SRC, OFFBASE, REGION, HALF, BUFN, KTN)                               \
    do {                                                                            \
        _Pragma("unroll")                                                           \
        for (int j = 0; j < 2; ++j) {                                               \
            gld_lds16((SRC) + (OFFBASE) + (size_t)((HALF) * 128 + j * 64) * 1024    \
                           + (size_t)(KTN) * 64,                                    \
                      &lds[BUFN][(REGION) + (HALF) * 8192 + j * 4096 + w * 512]);   \
        }                                                                           \
    } while (0)

#pragma unroll
    for (int h = 0; h < 2; ++h) {
#pragma unroll
        for (int j = 0; j < 2; ++j) {
            gld_lds16(A0 + aoff + (size_t)(h * 128 + j * 64) * 1024,
                      &lds[0][h * 8192 + j * 4096 + w * 512]);
            gld_lds16(B0 + boff + (size_t)(h * 128 + j * 64) * 1024,
                      &lds[0][16384 + h * 8192 + j * 4096 + w * 512]);
        }
    }

#define PHASE(MQ0, STAGECALL)                                                       \
    do {                                                                            \
        if (more) STAGECALL;                                                        \
        f16x8 p00 = *(const f16x8*)&Lb[abase + (MQ0) * 1024 + sl0];                 \
        f16x8 p01 = *(const f16x8*)&Lb[abase + (MQ0) * 1024 + sl1];                 \
        f16x8 p10 = *(const f16x8*)&Lb[abase + (MQ0 + 1) * 1024 + sl0];             \
        f16x8 p11 = *(const f16x8*)&Lb[abase + (MQ0 + 1) * 1024 + sl1];             \
        BAR();                                                                      \
        __builtin_amdgcn_s_setprio(1);                                              \
        _Pragma("unroll")                                                           \
        for (int ni = 0; ni < 4; ++ni) {                                            \
            acc[MQ0][ni] = mfma16h(p00, Bf0[ni], acc[MQ0][ni]);                     \
            acc[MQ0][ni] = mfma16h(p01, Bf1[ni], acc[MQ0][ni]);                     \
            acc[MQ0 + 1][ni] = mfma16h(p10, Bf0[ni], acc[MQ0 + 1][ni]);             \
            acc[MQ0 + 1][ni] = mfma16h(p11, Bf1[ni], acc[MQ0 + 1][ni]);             \
        }                                                                           \
        __builtin_amdgcn_s_setprio(0);                                              \
        BAR();                                                                      \
    } while (0)

#pragma unroll 1
    for (int t = 0; t < 32; ++t) {
        const int buf = t & 1;
        const int nbuf = buf ^ 1;
        const int tn = t + 1;
        const bool more = (tn < 32);
        const int termn = tn >> 4;
        const int ktn = tn & 15;
        const u16* An = termn ? A1 : A0;
        const u16* Bn = termn ? B1 : B0;
        const u16* Lb = &lds[buf][0];

        f16x8 Bf0[4], Bf1[4];

        if (more) STAGE2(An, aoff, 0, 0, nbuf, ktn);
        if (more) { VMCNT2; } else { VMCNT0; }
        BAR();
        {
            f16x8 a00 = *(const f16x8*)&Lb[abase + sl0];
            f16x8 a01 = *(const f16x8*)&Lb[abase + sl1];
            f16x8 a10 = *(const f16x8*)&Lb[abase + 1024 + sl0];
            f16x8 a11 = *(const f16x8*)&Lb[abase + 1024 + sl1];
#pragma unroll
            for (int ni = 0; ni < 4; ++ni) {
                Bf0[ni] = *(const f16x8*)&Lb[bbase + ni * 1024 + sl0];
                Bf1[ni] = *(const f16x8*)&Lb[bbase + ni * 1024 + sl1];
            }
            BAR();
            __builtin_amdgcn_s_setprio(1);
#pragma unroll
            for (int ni = 0; ni < 4; ++ni) {
                acc[0][ni] = mfma16h(a00, Bf0[ni], acc[0][ni]);
                acc[0][ni] = mfma16h(a01, Bf1[ni], acc[0][ni]);
                acc[1][ni] = mfma16h(a10, Bf0[ni], acc[1][ni]);
                acc[1][ni] = mfma16h(a11, Bf1[ni], acc[1][ni]);
            }
            __builtin_amdgcn_s_setprio(0);
            BAR();
        }
        PHASE(2, STAGE2(An, aoff, 0, 1, nbuf, ktn));
        PHASE(4, STAGE2(Bn, boff, 16384, 0, nbuf, ktn));
        PHASE(6, STAGE2(Bn, boff, 16384, 1, nbuf, ktn));
    }
#undef PHASE
#undef STAGE2

    if (z < 2) {
        u16* outp = (z == 0) ? args.outq : args.outk;
#pragma unroll
        for (int mq = 0; mq < 8; ++mq) {
#pragma unroll
            for (int ni = 0; ni < 4; ++ni) {
                const int e0 = ta * 256 + wa * 128 + mq * 16 + fg * 4;
                const int m = tb * 256 + wb * 64 + ni * 16 + fr;
                const int n = (m >> 11) * 16 + (e0 >> 6);
                const int s = m & 2047;
                u16x4 pk;
#pragma unroll
                for (int rr = 0; rr < 4; ++rr) pk[rr] = f2bf(acc[mq][ni][rr]);
                *(u16x4*)&outp[((size_t)(n * 2048 + s)) * 64 + (e0 & 63)] = pk;
            }
        }
    } else {
        u16* outp = args.outvt;
#pragma unroll
        for (int mq = 0; mq < 8; ++mq) {
#pragma unroll
            for (int ni = 0; ni < 4; ++ni) {
                const int m0 = ta * 256 + wa * 128 + mq * 16 + fg * 4;
                const int e = tb * 256 + wb * 64 + ni * 16 + fr;
                const int n = (m0 >> 11) * 16 + (e >> 6);
                u16x4 pk;
#pragma unroll
                for (int rr = 0; rr < 4; ++rr) pk[rr] = f2bf(acc[mq][ni][rr]);
                *(u16x4*)&outp[((size_t)(n * 64 + (e & 63))) * 2048 + (m0 & 2047)] = pk;
            }
        }
    }
}

// ---------------- Pass C: flash attention ----------------
// Swapped QK^T (softmax lane-local) AND swapped PV (acc^T: col=q=lane&15), so
// rescale/1-over-l are lane-local (no bpermute). Row-sum via all-ones A-frag MFMA.
__global__ __launch_bounds__(512, 4) void attn_kernel(const u16* __restrict__ qh,
                                                      const u16* __restrict__ kh,
                                                      const u16* __restrict__ vt,
                                                      float* __restrict__ out) {
    __shared__ u16 lds[2][16384];

    const int tid = threadIdx.x;
    const int w = tid >> 6, l = tid & 63;
    const int fr = l & 15, fg = l >> 4;

    const int b = blockIdx.x;
    const int n = (b & 7) * 4 + ((b >> 3) >> 4);
    const int qt = (b >> 3) & 15;
    const int qbase = qt * 128 + w * 16;
    const float cs = 0.125f * 1.44269504088896f;

    const u16* khn = kh + (size_t)n * 2048 * 64;
    const u16* vtn = vt + (size_t)n * 64 * 2048;

    const u16* qrow = qh + ((size_t)n * 2048 + qbase + fr) * 64;
    bf16x8 aq0 = *(const bf16x8*)(qrow + fg * 8);
    bf16x8 aq1 = *(const bf16x8*)(qrow + 32 + fg * 8);

    bf16x8 ones;
#pragma unroll
    for (int j = 0; j < 8; ++j) ones[j] = (short)0x3F80;

    const int krow_s = tid >> 2;
    const int kcol_s = (tid & 3) * 16;
    const int kg_s = ((tid >> 2) & 3) + 4 * ((tid >> 5) & 1);
    const int kws0 = ((((tid & 3) * 2 + 0) + kg_s) & 7) * 8;
    const int kws1 = ((((tid & 3) * 2 + 1) + kg_s) & 7) * 8;
    const int vrow_s = tid >> 3;
    const int vcol_s = (tid & 7) * 16;
    const int vg_s = (tid >> 3) & 7;
    const int vws0 = ((((tid & 7) * 2 + 0) + vg_s) & 15) * 8;
    const int vws1 = ((((tid & 7) * 2 + 1) + vg_s) & 15) * 8;

    const int rbase = ((fr >> 2) << 3) + (fr & 3);
    const int kg_r = (fr & 3) + 4 * ((fr >> 2) & 1);
    const int ksl0 = (((fg + 0) + kg_r) & 7) * 8;
    const int ksl1 = (((fg + 4) + kg_r) & 7) * 8;
    const int vg_r = fr & 7;

    // acc[0..3] = D^T[d-block][q], acc[4] = running row-sum (ones-MFMA)
    f32x4 acc[5];
#pragma unroll
    for (int dc = 0; dc < 5; ++dc) acc[dc] = (f32x4){0.f, 0.f, 0.f, 0.f};
    float mrun = -INFINITY;

    bf16x8 kr0, kr1, vr0, vr1;

#define STAGE_LOAD(kb_) do {                                                       \
        const u16* ksrc = khn + ((size_t)((kb_) * 128 + krow_s)) * 64 + kcol_s;    \
        kr0 = *(const bf16x8*)(ksrc);                                              \
        kr1 = *(const bf16x8*)(ksrc + 8);                                          \
        const u16* vsrc = vtn + (size_t)vrow_s * 2048 + (kb_) * 128 + vcol_s;      \
        vr0 = *(const bf16x8*)(vsrc);                                              \
        vr1 = *(const bf16x8*)(vsrc + 8);                                          \
    } while (0)

#define STAGE_WRITE(buf_) do {                                                     \
        u16* kp = &lds[buf_][0];                                                   \
        *(bf16x8*)&kp[krow_s * 64 + kws0] = kr0;                                   \
        *(bf16x8*)&kp[krow_s * 64 + kws1] = kr1;                                   \
        u16* vp = &lds[buf_][8192];                                                \
        *(bf16x8*)&vp[vrow_s * 128 + vws0] = vr0;                                  \
        *(bf16x8*)&vp[vrow_s * 128 + vws1] = vr1;                                  \
    } while (0)

    STAGE_LOAD(0);
    STAGE_WRITE(0);
    STAGE_LOAD(1);
    __syncthreads();

    for (int kb = 0; kb < 16; ++kb) {
        const int cur = kb & 1;
        const u16* Kb = &lds[cur][0];
        const u16* Vb = &lds[cur][8192];

        f32x4 sf[8];
#pragma unroll
        for (int c = 0; c < 8; ++c) {
            const int rr = ((c >> 1) << 5) + ((c & 1) << 2) + rbase;
            f32x4 s = (f32x4){0.f, 0.f, 0.f, 0.f};
            s = mfma16(*(const bf16x8*)&Kb[rr * 64 + ksl0], aq0, s);
            s = mfma16(*(const bf16x8*)&Kb[rr * 64 + ksl1], aq1, s);
            sf[c] = s;
        }

        f32x4 cmv = sf[0];
#pragma unroll
        for (int c = 1; c < 8; ++c)
#pragma unroll
            for (int rr = 0; rr < 4; ++rr) cmv[rr] = fmaxf(cmv[rr], sf[c][rr]);
        float cm = fmaxf(fmaxf(cmv[0], cmv[1]), fmaxf(cmv[2], cmv[3]));
        cm = fmaxf(cm, __shfl_xor(cm, 16, 64));
        cm = fmaxf(cm, __shfl_xor(cm, 32, 64));

        if (__any(cm > mrun)) {
            float mnew = fmaxf(mrun, cm);
            float sc = fexp2(cs * (mrun - mnew));
            mrun = mnew;
#pragma unroll
            for (int dc = 0; dc < 5; ++dc)
#pragma unroll
                for (int rr = 0; rr < 4; ++rr) acc[dc][rr] *= sc;
        }

        const float negm = -cs * mrun;
#pragma unroll
        for (int c = 0; c < 8; ++c) {
#pragma unroll
            for (int rr = 0; rr < 4; ++rr)
                sf[c][rr] = fexp2(fmaf(cs, sf[c][rr], negm));
        }

#pragma unroll
        for (int pw = 0; pw < 4; ++pw) {
            union { bf16x8 v; uint32_t u[4]; } ap;
#pragma unroll
            for (int q2 = 0; q2 < 4; ++q2) {
                float lo = sf[2 * pw + (q2 >> 1)][(q2 & 1) * 2 + 0];
                float hi = sf[2 * pw + (q2 >> 1)][(q2 & 1) * 2 + 1];
                asm("v_cvt_pk_bf16_f32 %0, %1, %2" : "=v"(ap.u[q2]) : "v"(lo), "v"(hi));
            }
#pragma unroll
            for (int dc = 0; dc < 4; ++dc) {
                const int vsl = (((pw * 4 + fg) + vg_r) & 15) * 8;
                acc[dc] = mfma16(*(const bf16x8*)&Vb[(dc * 16 + fr) * 128 + vsl],
                                 ap.v, acc[dc]);
            }
            acc[4] = mfma16(ones, ap.v, acc[4]);
        }

        if (kb < 15) {
            __syncthreads();
            STAGE_WRITE(cur ^ 1);
            if (kb < 14) STAGE_LOAD(kb + 2);
            __syncthreads();
        }
    }

    // ---- finalize: everything lane-local in acc^T form ----
    const float inv = 1.f / acc[4][0];
    const int bq = n & 1;
    const int col0 = (n >> 1) * 64;
    float* orow = out + ((size_t)bq * 2048 + qbase + fr) * 1024 + col0 + fg * 4;
#pragma unroll
    for (int dblk = 0; dblk < 4; ++dblk) {
        f4v o;
#pragma unroll
        for (int rr = 0; rr < 4; ++rr) o[rr] = acc[dblk][rr] * inv;
        *(f4v*)&orow[dblk * 16] = o;
    }
#undef STAGE_LOAD
#undef STAGE_WRITE
}

// ---------------- launch ----------------
extern "C" void kernel_launch(void* const* d_in, const int* in_sizes, int n_in,
                              void* d_out, int out_size, void* d_ws, size_t ws_size,
                              hipStream_t stream) {
    (void)n_in; (void)out_size; (void)ws_size;
    const float* q  = (const float*)d_in[0];
    const float* k  = (const float*)d_in[1];
    const float* v  = (const float*)d_in[2];
    const float* Wq = (const float*)d_in[3];
    const float* Wk = (const float*)d_in[4];
    const float* Wv = (const float*)d_in[5];

    uint8_t* ws = (uint8_t*)d_ws;
    const size_t MB = 1024ull * 1024ull;
    u16* xq_hi = (u16*)(ws + 0 * MB);
    u16* xq_lo = (u16*)(ws + 8 * MB);
    u16* xk_hi = (u16*)(ws + 16 * MB);
    u16* xk_lo = (u16*)(ws + 24 * MB);
    u16* xv_hi = (u16*)(ws + 32 * MB);
    u16* xv_lo = (u16*)(ws + 40 * MB);
    u16* wq_f  = (u16*)(ws + 48 * MB);
    u16* wk_f  = (u16*)(ws + 50 * MB);
    u16* wv_f  = (u16*)(ws + 52 * MB);
    u16* qh    = (u16*)(ws + 54 * MB);
    u16* kh    = (u16*)(ws + 62 * MB);
    u16* vt    = (u16*)(ws + 70 * MB);

    SplitArgs sx;
    sx.src[0] = q;  sx.src[1] = k;  sx.src[2] = v;
    sx.hi[0] = xq_hi; sx.hi[1] = xk_hi; sx.hi[2] = xv_hi;
    sx.lo[0] = xq_lo; sx.lo[1] = xk_lo; sx.lo[2] = xv_lo;
    sx.n4 = in_sizes[0] / 4;
    splitx_kernel<<<dim3(2048, 3), 256, 0, stream>>>(sx);

    CastArgs cw;
    cw.src[0] = Wq; cw.src[1] = Wk; cw.src[2] = Wv;
    cw.dst[0] = wq_f; cw.dst[1] = wk_f; cw.dst[2] = wv_f;
    cw.n4 = in_sizes[3] / 4;
    castw_kernel<<<dim3(512, 3), 256, 0, stream>>>(cw);

    ProjArgs pa;
    pa.xhi[0] = xq_hi; pa.xhi[1] = xk_hi; pa.xhi[2] = xv_hi;
    pa.xlo[0] = xq_lo; pa.xlo[1] = xk_lo; pa.xlo[2] = xv_lo;
    pa.wf[0] = wq_f; pa.wf[1] = wk_f; pa.wf[2] = wv_f;
    pa.outq = qh; pa.outk = kh; pa.outvt = vt;
    proj_kernel<<<dim3(192), 512, 0, stream>>>(pa);

    attn_kernel<<<dim3(512), 512, 0, stream>>>(qh, kh, vt, (float*)d_out);
}